// Round 1
// baseline (14701.172 us; speedup 1.0000x reference)
//
#include <hip/hip_runtime.h>
#include <hip/hip_bf16.h>

typedef __bf16 bf16x8 __attribute__((ext_vector_type(8)));
typedef float f32x4 __attribute__((ext_vector_type(4)));

__device__ __forceinline__ float b2f(ushort u){
  union { uint u; float f; } x; x.u = ((uint)u) << 16; return x.f;
}
__device__ __forceinline__ ushort f2b(float f){
  union { float f; uint u; } x; x.f = f;
  uint r = x.u + 0x7fff + ((x.u >> 16) & 1);
  return (ushort)(r >> 16);
}
__device__ __forceinline__ uint pack_bf2(float a, float b){
  return (uint)f2b(a) | ((uint)f2b(b) << 16);
}
__device__ __forceinline__ float lo16(uint u){ union{uint a;float f;}x; x.a=u<<16; return x.f; }
__device__ __forceinline__ float hi16(uint u){ union{uint a;float f;}x; x.a=u&0xffff0000u; return x.f; }
__device__ __forceinline__ float gelu_exact(float v){
  return 0.5f * v * (1.0f + erff(v * 0.70710678118654752f));
}

// ---------------------------------------------------------------------------
// 64x64-tile MFMA bf16 GEMM (unchanged)
// ---------------------------------------------------------------------------
template<int AF32, int ACT>
__global__ __launch_bounds__(256) void gemm_kernel(
    const void* __restrict__ Av, const float* __restrict__ W, int ldw,
    const float* __restrict__ bias, const float* residf,
    float* Cf, ushort* Cb,
    int M, int N, int K, float scale)
{
  __shared__ __align__(16) ushort Al[64*40];
  __shared__ __align__(16) ushort Bl[64*40];
  const int nb = N >> 6;
  const int rb = blockIdx.x / nb, cb = blockIdx.x % nb;
  const int tid = threadIdx.x;
  const int w = tid >> 6, l = tid & 63;
  f32x4 acc[4];
#pragma unroll
  for(int i=0;i<4;i++) acc[i] = (f32x4){0.f,0.f,0.f,0.f};
  const int ar = tid >> 2, ai = (tid & 3) << 3;
  const int bk = tid >> 3, bn = (tid & 7) << 3;
  for(int kb = 0; kb < K; kb += 32){
    uint4 au;
    if(AF32){
      const float* Ap = (const float*)Av + (size_t)(rb*64 + ar)*K + kb + ai;
      float4 f0 = *(const float4*)Ap;
      float4 f1 = *(const float4*)(Ap + 4);
      au.x = pack_bf2(f0.x,f0.y); au.y = pack_bf2(f0.z,f0.w);
      au.z = pack_bf2(f1.x,f1.y); au.w = pack_bf2(f1.z,f1.w);
    } else {
      au = *(const uint4*)((const ushort*)Av + (size_t)(rb*64 + ar)*K + kb + ai);
    }
    const float* Wp = W + (size_t)(kb + bk)*ldw + cb*64 + bn;
    float4 w0 = *(const float4*)Wp;
    float4 w1 = *(const float4*)(Wp + 4);
    ushort bs[8];
    bs[0]=f2b(w0.x); bs[1]=f2b(w0.y); bs[2]=f2b(w0.z); bs[3]=f2b(w0.w);
    bs[4]=f2b(w1.x); bs[5]=f2b(w1.y); bs[6]=f2b(w1.z); bs[7]=f2b(w1.w);
    __syncthreads();
    *(uint4*)&Al[ar*40 + ai] = au;
#pragma unroll
    for(int i=0;i<8;i++) Bl[(bn+i)*40 + bk] = bs[i];
    __syncthreads();
    bf16x8 af = *(const bf16x8*)&Al[(w*16 + (l&15))*40 + (l>>4)*8];
#pragma unroll
    for(int c4=0;c4<4;c4++){
      bf16x8 bfv = *(const bf16x8*)&Bl[(c4*16 + (l&15))*40 + (l>>4)*8];
      acc[c4] = __builtin_amdgcn_mfma_f32_16x16x32_bf16(af, bfv, acc[c4], 0,0,0);
    }
  }
#pragma unroll
  for(int c4=0;c4<4;c4++){
#pragma unroll
    for(int r=0;r<4;r++){
      int row = rb*64 + w*16 + (l>>4)*4 + r;
      int col = cb*64 + c4*16 + (l&15);
      size_t idx = (size_t)row*N + col;
      float vv = acc[c4][r];
      if(bias) vv += bias[col];
      vv *= scale;
      if(residf) vv += residf[idx];
      if(ACT) vv = gelu_exact(vv);
      if(Cf) Cf[idx] = vv;
      if(Cb) Cb[idx] = f2b(vv);
    }
  }
}

// ---------------------------------------------------------------------------
// Causal self-attention (unchanged)
// ---------------------------------------------------------------------------
__global__ __launch_bounds__(256) void attn_kernel(const ushort* __restrict__ Q,
    const ushort* __restrict__ K, const ushort* __restrict__ V, ushort* __restrict__ O)
{
  __shared__ float s[16*520];
  __shared__ float kt[64*66];
  __shared__ float rowm[16], rowr[16], redx[256];
  const int bid = blockIdx.x;
  const int qb = bid & 31, h = (bid>>5)&3, b = bid>>7;
  const int tid = threadIdx.x;
  const int qi = tid >> 4, jj = tid & 15;
  const int qrow = qb*16 + qi;
  float qreg[64];
  {
    const ushort* qp = Q + ((size_t)(b*512 + qrow))*256 + h*64;
#pragma unroll
    for(int d=0; d<64; d++) qreg[d] = b2f(qp[d])*0.125f;
  }
  const int ntile = (qb*16 + 79) >> 6;
  for(int jt=0; jt<ntile; jt++){
    {
      int jr = tid >> 2, d0 = (tid & 3) << 4;
      const ushort* kp = K + ((size_t)(b*512 + jt*64 + jr))*256 + h*64 + d0;
#pragma unroll
      for(int i=0;i<16;i++) kt[jr*66 + d0 + i] = b2f(kp[i]);
    }
    __syncthreads();
#pragma unroll
    for(int jl=0;jl<4;jl++){
      int jloc = jj*4 + jl;
      int j = jt*64 + jloc;
      float a = 0.f;
#pragma unroll
      for(int d=0; d<64; d++) a += qreg[d]*kt[jloc*66 + d];
      s[qi*520 + j] = (j <= qrow) ? a : -1e30f;
    }
    __syncthreads();
  }
  const int nj = ntile*64;
  float m = -1e30f;
  for(int j=jj; j<nj; j+=16) m = fmaxf(m, s[qi*520 + j]);
  redx[jj*16 + qi] = m;
  __syncthreads();
  if(tid < 16){
    float mm = -1e30f;
#pragma unroll
    for(int k2=0;k2<16;k2++) mm = fmaxf(mm, redx[k2*16 + tid]);
    rowm[tid] = mm;
  }
  __syncthreads();
  float mrow = rowm[qi];
  float ssum = 0.f;
  for(int j=jj; j<nj; j+=16){
    float e = __expf(s[qi*520+j] - mrow);
    s[qi*520+j] = e; ssum += e;
  }
  redx[jj*16 + qi] = ssum;
  __syncthreads();
  if(tid < 16){
    float t2 = 0.f;
#pragma unroll
    for(int k2=0;k2<16;k2++) t2 += redx[k2*16 + tid];
    rowr[tid] = 1.0f/t2;
  }
  const int dd = jj;
  float acc4[4] = {0,0,0,0};
  for(int jt=0; jt<ntile; jt++){
    __syncthreads();
    {
      int jr = tid >> 2, d0 = (tid & 3) << 4;
      const ushort* vp = V + ((size_t)(b*512 + jt*64 + jr))*256 + h*64 + d0;
#pragma unroll
      for(int i=0;i<16;i++) kt[jr*66 + d0 + i] = b2f(vp[i]);
    }
    __syncthreads();
#pragma unroll
    for(int jl=0;jl<64;jl++){
      float p = s[qi*520 + jt*64 + jl];
#pragma unroll
      for(int i=0;i<4;i++) acc4[i] += p*kt[jl*66 + dd*4 + i];
    }
  }
  float rr = rowr[qi];
  ushort* op = O + ((size_t)(b*512 + qrow))*256 + h*64 + dd*4;
#pragma unroll
  for(int i=0;i<4;i++) op[i] = f2b(acc4[i]*rr);
}

// ---------------------------------------------------------------------------
// LayerNorm / small kernels (unchanged)
// ---------------------------------------------------------------------------
__global__ __launch_bounds__(256) void ln_kernel(const float* __restrict__ in,
    const float* __restrict__ g, const float* __restrict__ be,
    float* outf, ushort* outb)
{
  int row = blockIdx.x*4 + (threadIdx.x>>6);
  int lane = threadIdx.x & 63;
  size_t idx = (size_t)row*256 + lane*4;
  float4 v = *(const float4*)(in + idx);
  float s1 = v.x+v.y+v.z+v.w;
  float s2 = v.x*v.x + v.y*v.y + v.z*v.z + v.w*v.w;
#pragma unroll
  for(int off=32; off; off>>=1){ s1 += __shfl_xor(s1,off); s2 += __shfl_xor(s2,off); }
  float mu = s1*(1.f/256.f);
  float var = s2*(1.f/256.f) - mu*mu;
  float r = rsqrtf(var + 1e-5f);
  float vals[4] = {v.x,v.y,v.z,v.w};
  float4 o4; ushort4 ob;
  float* oo = (float*)&o4; ushort* obp = (ushort*)&ob;
#pragma unroll
  for(int i=0;i<4;i++){
    int d = lane*4 + i;
    float y = (vals[i]-mu)*r*g[d] + be[d];
    oo[i] = y; obp[i] = f2b(y);
  }
  if(outf) *(float4*)(outf+idx) = o4;
  if(outb) *(ushort4*)(outb+idx) = ob;
}

__global__ void guid_kernel(const float* __restrict__ h0, const float* __restrict__ spw,
                            const float* __restrict__ spb, float* __restrict__ guid)
{
  int b = blockIdx.x, c = threadIdx.x;
  float s = spb[c];
  for(int r=0;r<256;r++) s += h0[b*256+r]*spw[r*256+c];
  guid[b*256+c] = s;
}

__global__ void ffnin_kernel(const float* __restrict__ x1, const float* __restrict__ guid,
                             ushort* __restrict__ out)
{
  size_t base = ((size_t)blockIdx.x*256 + threadIdx.x)*8;
  int row = (int)(base >> 8); int bb = row >> 9; int c = (int)(base & 255);
  float4 v0 = *(const float4*)(x1 + base);
  float4 v1 = *(const float4*)(x1 + base + 4);
  const float* gp = guid + bb*256 + c;
  const float* xs = (const float*)&v0;
  ushort o[8];
#pragma unroll
  for(int i=0;i<4;i++) o[i] = f2b(xs[i] + 0.3f*gp[i]);
  const float* xs1 = (const float*)&v1;
#pragma unroll
  for(int i=0;i<4;i++) o[4+i] = f2b(xs1[i] + 0.3f*gp[4+i]);
  *(uint4*)(out + base) = *(uint4*)o;
}

__global__ void bo_kernel(const float* __restrict__ ta_bo, const float* __restrict__ tr_w1,
                          float* __restrict__ bo_f)
{
  int c = threadIdx.x;
  float s = 0.f;
  for(int m=0;m<256;m++) s += ta_bo[m]*tr_w1[(size_t)(256+m)*512 + c];
  bo_f[c] = s;
}

// ---------------------------------------------------------------------------
// Persistent scan, ONE-HOP design. 64 blocks x 512 threads, block = (batch,head).
// Each block: own-head attention ctx -> 512-wide FFN-hidden PARTIAL (ctx_hd @
// Wf[hd*64..]) -> single global exchange of partials -> gelu + FULL w2 matvec
// + LN3 replicated in every block (h is bitwise identical across the 4 blocks
// of a batch, so no second hop). Score dot-products for step t+1 (rows <= t-1)
// are computed in the shadow of the exchange wait; the last row's score comes
// from the k-projection registers via cross-wave shuffle at step end.
// Registers: wp(32) + wfp(32) + w2p(128) packed bf16-pair uints.
// Flags: [0..511] fast per-wave (b4+hd)*8+w, [512..1023] shadow (cross-XCD),
//        [1024..1087] xcc table. psum double-buffered by t&1.
// ---------------------------------------------------------------------------
__global__ __launch_bounds__(512, 1) void scan_kernel(
    const ushort* __restrict__ qtb, const ushort* __restrict__ Ubf,
    const float* __restrict__ Wf, const float* __restrict__ bo_f,
    float* psum, int* flags,
    const float* __restrict__ ta_wk, const float* __restrict__ ta_wv,
    const float* __restrict__ ta_bk, const float* __restrict__ ta_bv,
    const float* __restrict__ tr_w2, const float* __restrict__ tr_b2,
    const float* __restrict__ ln3_g, const float* __restrict__ ln3_b,
    const float* __restrict__ ln4_g, const float* __restrict__ ln4_b,
    const float* __restrict__ h0, float* __restrict__ out_h)
{
  __shared__ __align__(16) float red[1024];
  __shared__ float pbuf[512];
  __shared__ __align__(16) float hbuf[256];
  __shared__ float ctxS[64];
  __shared__ float qbufS[2][64];
  __shared__ float glbuf[512];
  __shared__ float deltaS[256];
  __shared__ float lnG[256], lnB[256], b2S[256];
  __shared__ float misc[32];
  __shared__ int cp_same[4];
  extern __shared__ __align__(16) ushort dynL[];
  ushort* kcL = dynL;             // [512][66] u16 (this head's K cache)
  ushort* vcL = dynL + 512*66;    // [512][66] u16 (this head's V cache)

  const int tid = threadIdx.x;
  const int bid = blockIdx.x;
  const int b   = bid & 15;
  const int hd  = bid >> 4;
  const int b4  = b*4;
  const int w8  = tid >> 6;

  for(int i = tid; i < 256; i += 512){
    hbuf[i] = h0[b*256 + i];
    lnG[i] = ln3_g[i]; lnB[i] = ln3_b[i]; b2S[i] = tr_b2[i];
  }

  // ---- one-time XCD handshake ----
  int myxcc;
  asm volatile("s_getreg_b32 %0, hwreg(HW_REG_XCC_ID)" : "=s"(myxcc));
  if(tid == 0)
    __hip_atomic_store(&flags[1024 + bid], myxcc + 1, __ATOMIC_RELEASE, __HIP_MEMORY_SCOPE_AGENT);
  if(tid < 4){
    int v;
    while((v = __hip_atomic_load(&flags[1024 + tid*16 + b], __ATOMIC_ACQUIRE, __HIP_MEMORY_SCOPE_AGENT)) == 0)
      __builtin_amdgcn_s_sleep(8);
    cp_same[tid] = ((v - 1) == myxcc);
  }

  // ---- per-thread weight registers ----
  // k/v matvec: thread = out*4 + sX; out<64 -> k col, out>=64 -> v col.
  const int out = tid >> 2, sX = tid & 3;
  const int kvSel = out >> 6, colX = out & 63;
  const float* WX = kvSel ? ta_wv : ta_wk;
  uint wp[32];
#pragma unroll
  for(int i=0;i<32;i++){
    int r0 = 8*i + 2*sX;
    wp[i] = pack_bf2(WX[(size_t)r0*256 + hd*64 + colX],
                     WX[(size_t)(r0+1)*256 + hd*64 + colX]);
  }
  const float pbX = kvSel ? ta_bv[hd*64 + colX] : ta_bk[hd*64 + colX];

  // partial1: thread = hidden col (512), own-head ctx rows hd*64..hd*64+63.
  uint wfp[32];
#pragma unroll
  for(int i=0;i<32;i++){
    int r0 = hd*64 + 2*i;
    wfp[i] = pack_bf2(Wf[(size_t)r0*512 + tid], Wf[(size_t)(r0+1)*512 + tid]);
  }
  const float bo_r = bo_f[tid];

  // full w2 matvec (replicated): thread = dcol*2 + s2, rows 4i+2*s2 (+1).
  const int dcol = tid >> 1, s2 = tid & 1;
  uint w2p[128];
#pragma unroll
  for(int i=0;i<128;i++){
    int r0 = 4*i + 2*s2;
    w2p[i] = pack_bf2(tr_w2[(size_t)r0*256 + dcol], tr_w2[(size_t)(r0+1)*256 + dcol]);
  }

  __syncthreads();
  const int anyrem = !(cp_same[0] & cp_same[1] & cp_same[2] & cp_same[3]);

  // hoisted comm pointers
  volatile int* myf = (volatile int*)&flags[(b4 + hd)*8 + w8];
  const int qa = (hd+1)&3, qb2 = (hd+2)&3, qc2 = (hd+3)&3;
  volatile int* fA = (volatile int*)&flags[(b4 + qa)*8 + w8];
  volatile int* fB = (volatile int*)&flags[(b4 + qb2)*8 + w8];
  volatile int* fC = (volatile int*)&flags[(b4 + qc2)*8 + w8];
  float* psw = psum + (size_t)(b4 + hd)*1024 + tid;   // + (t&1)*512
  const float* psr = psum + (size_t)b4*1024 + tid;    // + q*1024 + (t&1)*512

  // q prefetch (row 1) — wave 7 stages q into LDS each step
  ushort qpre = 0;
  if(tid >= 448) qpre = qtb[((size_t)(b*512 + 1))*256 + hd*64 + (tid - 448)];
  float scv = -3.0e38f;   // shadow score (this thread's row) for next step

#pragma clang loop unroll(disable)
  for(int t = 0; t < 512; ++t){
    // top: stage q_{t+1} into LDS slot (t+1)&1; issue q_{t+2} load; issue Ubf[t]
    if(tid >= 448){
      qbufS[(t+1)&1][tid-448] = b2f(qpre)*0.125f;
      int tq = (t+2 < 512) ? (t+2) : 511;
      qpre = qtb[((size_t)(b*512 + tq))*256 + hd*64 + (tid - 448)];
    }
    float ub = b2f(Ubf[((size_t)(b*512 + t))*512 + tid]);

    if(t > 0){
      // [A] finalize scores: shadow regs + last row from misc[16..19]
      float s = scv;
      if(tid == t-1) s = (misc[16]+misc[17]) + (misc[18]+misc[19]);
      // [B] per-wave online softmax
      float wm = s;
#pragma unroll
      for(int off=32; off; off>>=1) wm = fmaxf(wm, __shfl_xor(wm, off));
      float e = __expf(s - wm);
      float ws = e;
#pragma unroll
      for(int off=32; off; off>>=1) ws += __shfl_xor(ws, off);
      pbuf[tid] = e;
      if((tid & 63) == 0){ misc[w8] = wm; misc[8 + w8] = ws; }
      __syncthreads();                                   // S1
      float gm = misc[0];
#pragma unroll
      for(int i=1;i<8;i++) gm = fmaxf(gm, misc[i]);
      float gsum = 0.f;
#pragma unroll
      for(int i=0;i<8;i++) gsum += misc[8+i]*__expf(misc[i]-gm);
      float rsum = 1.0f / gsum;
      // [C1] ctx partials: group g handles 32 j's, lane l -> d-pair (2l,2l+1)
      {
        const int g = tid >> 5, l = tid & 31;
        float sfac = __expf(misc[g>>1] - gm);
        int nn = t - g*32; nn = nn < 0 ? 0 : (nn > 32 ? 32 : nn);
        float a0 = 0.f, a1 = 0.f;
        const uint* vbase = (const uint*)vcL;
#pragma unroll 4
        for(int i=0;i<nn;i++){
          int j2 = g*32 + i;
          uint vv = vbase[j2*33 + l];
          float p = pbuf[j2];
          a0 += p*lo16(vv); a1 += p*hi16(vv);
        }
        float2 pr; pr.x = a0*sfac; pr.y = a1*sfac;
        *(float2*)&red[g*64 + 2*l] = pr;
      }
      __syncthreads();                                   // S2
      if(tid < 64){
        float cv = 0.f;
#pragma unroll
        for(int g2=0; g2<16; g2++) cv += red[g2*64 + tid];
        ctxS[tid] = cv * rsum;
      }
      __syncthreads();                                   // S3
      // [C2] hidden partial = ctx_hd (64) @ Wf slice -> psum store
      {
        float acc = 0.f;
#pragma unroll
        for(int i=0;i<32;i++){
          float2 c2 = *(const float2*)&ctxS[2*i];
          acc += c2.x*lo16(wfp[i]) + c2.y*hi16(wfp[i]);
        }
        psw[(t&1)*512] = acc;
      }
      // [D1] shadow: score dots for q_{t+1}, rows j=tid <= t-1
      //      (hides the psum store latency before the vmcnt drain)
      if(tid < t){
        const uint* kr = (const uint*)(kcL + tid*66);
        const float* qS = qbufS[(t+1)&1];
        float a = 0.f;
#pragma unroll
        for(int w=0; w<32; w++){
          uint kk = kr[w];
          float2 q2 = *(const float2*)&qS[2*w];
          a += q2.x*lo16(kk) + q2.y*hi16(kk);
        }
        scv = a;
      } else scv = -3.0e38f;
      // [D2] per-wave flag (own stores drained)
      asm volatile("s_waitcnt vmcnt(0)" ::: "memory");
      if((tid & 63) == 0){
        *myf = t;
        if(anyrem)
          __hip_atomic_store(&flags[512 + (b4 + hd)*8 + w8], t, __ATOMIC_RELEASE, __HIP_MEMORY_SCOPE_AGENT);
      }
      // [D3] poll peers (flags are wave-uniform)
      if(!anyrem){
        while(*fA < t || *fB < t || *fC < t) __builtin_amdgcn_s_sleep(1);
      } else {
#pragma unroll
        for(int qq=1; qq<4; qq++){
          int q = (hd+qq)&3;
          if(cp_same[q]){
            while(*(volatile int*)&flags[(b4+q)*8 + w8] < t) __builtin_amdgcn_s_sleep(1);
          } else {
            while(__hip_atomic_load(&flags[512 + (b4+q)*8 + w8], __ATOMIC_RELAXED, __HIP_MEMORY_SCOPE_AGENT) < t)
              __builtin_amdgcn_s_sleep(2);
          }
        }
        __builtin_amdgcn_fence(__ATOMIC_ACQUIRE, "agent");
      }
      // [D4] gather 4 partials (fixed q order => bitwise-identical g1 in all blocks)
      {
        const float* pr2 = psr + (t&1)*512;
        float r0 = *(volatile const float*)(pr2);
        float r1 = *(volatile const float*)(pr2 + 1024);
        float r2 = *(volatile const float*)(pr2 + 2048);
        float r3 = *(volatile const float*)(pr2 + 3072);
        glbuf[tid] = gelu_exact(ub + bo_r + ((r0+r1)+(r2+r3)));
      }
    } else {
      glbuf[tid] = gelu_exact(ub);   // t==0: ctx zeroed (no bo, no partials)
      scv = -3.0e38f;
    }
    __syncthreads();                                     // S4
    // [E] full w2 matvec (replicated)
    {
      float dp = 0.f;
#pragma unroll
      for(int i=0;i<128;i++){
        float2 gv = *(const float2*)&glbuf[4*i + 2*s2];
        dp += gv.x*lo16(w2p[i]) + gv.y*hi16(w2p[i]);
      }
      dp += __shfl_xor(dp, 1);
      if(s2 == 0) deltaS[dcol] = dp;
    }
    __syncthreads();                                     // S5
    // [F] LN3 (wave 0): h_{t+1} = LN(h_t + 0.5*(delta + tr_b2))
    if(tid < 64){
      float v4[4]; float s1 = 0.f, sq = 0.f;
#pragma unroll
      for(int c=0;c<4;c++){
        int d = 4*tid + c;
        float vv = hbuf[d] + 0.5f*(deltaS[d] + b2S[d]);
        v4[c] = vv; s1 += vv; sq += vv*vv;
      }
#pragma unroll
      for(int off=32; off; off>>=1){ s1 += __shfl_xor(s1,off); sq += __shfl_xor(sq,off); }
      float mu = s1*(1.f/256.f);
      float var = sq*(1.f/256.f) - mu*mu;
      float rstd = rsqrtf(var + 1e-5f);
#pragma unroll
      for(int c=0;c<4;c++){
        int d = 4*tid + c;
        hbuf[d] = (v4[c]-mu)*rstd*lnG[d] + lnB[d];
      }
    }
    __syncthreads();                                     // S6
    // [G] k/v row t from h_{t+1}; also next step's last-row score partial
    {
      float acc = 0.f;
#pragma unroll
      for(int i=0;i<32;i++){
        float2 hv = *(const float2*)&hbuf[8*i + 2*sX];
        acc += hv.x*lo16(wp[i]) + hv.y*hi16(wp[i]);
      }
      acc += __shfl_xor(acc, 1);
      acc += __shfl_xor(acc, 2);
      float kf = acc + pbX;
      if(sX == 0){
        ushort u = f2b(kf);
        if(kvSel == 0) kcL[t*66 + colX] = u;
        else           vcL[t*66 + colX] = u;
      }
      float pv = (kvSel == 0 && sX == 0) ? qbufS[(t+1)&1][colX]*kf : 0.f;
      pv += __shfl_xor(pv, 4);
      pv += __shfl_xor(pv, 8);
      pv += __shfl_xor(pv, 16);
      pv += __shfl_xor(pv, 32);
      if(tid < 256 && (tid & 63) == 0) misc[16 + w8] = pv;
    }
    __syncthreads();                                     // S7
  } // t loop

  // final LN4 (every block has the full h; only hd==0 writes)
  if(hd == 0 && tid < 64){
    float v4[4]; float s1 = 0.f, sq = 0.f;
#pragma unroll
    for(int c=0;c<4;c++){ float vv = hbuf[4*tid + c]; v4[c]=vv; s1 += vv; sq += vv*vv; }
#pragma unroll
    for(int off=32; off; off>>=1){ s1 += __shfl_xor(s1,off); sq += __shfl_xor(sq,off); }
    float mu = s1*(1.f/256.f);
    float var = sq*(1.f/256.f) - mu*mu;
    float rstd = rsqrtf(var + 1e-5f);
#pragma unroll
    for(int c=0;c<4;c++){
      int d = 4*tid + c;
      out_h[b*256 + d] = (v4[c]-mu)*rstd*ln4_g[d] + ln4_b[d];
    }
  }
}

// ---------------------------------------------------------------------------
// Workspace layout (bytes).
// ---------------------------------------------------------------------------
#define OFF_FLAGS ((size_t)0)          // 8 KiB  (fast 512 | shadow 512 | xcc 64)
#define OFF_BOF   ((size_t)8192)       // 2 KiB
#define OFF_PSUM  ((size_t)16384)      // 16*4*2*512*4 = 256 KiB
#define OFF_GUID  ((size_t)278528)     // 16 KiB
#define OFF_WF    ((size_t)294912)     // 512 KiB -> ends 819200
#define OFF_Z1    ((size_t)(1u<<20))
#define OFF_Z2    ((size_t)(5u<<20))
#define OFF_Z3    ((size_t)(9u<<20))
#define OFF_Z4    ((size_t)(13u<<20))
#define OFF_M     ((size_t)(17u<<20))

#define SCAN_DYN_LDS (512*66*2*2)   // 135168 B

extern "C" void kernel_launch(void* const* d_in, const int* in_sizes, int n_in,
                              void* d_out, int out_size, void* d_ws, size_t ws_size,
                              hipStream_t stream)
{
  const float* x     = (const float*)d_in[0];
  const float* h0    = (const float*)d_in[1];
  const float* sa_wq = (const float*)d_in[2];
  const float* sa_wk = (const float*)d_in[3];
  const float* sa_wv = (const float*)d_in[4];
  const float* sa_wo = (const float*)d_in[5];
  const float* sa_bq = (const float*)d_in[6];
  const float* sa_bk = (const float*)d_in[7];
  const float* sa_bv = (const float*)d_in[8];
  const float* sa_bo = (const float*)d_in[9];
  const float* f_w1  = (const float*)d_in[10];
  const float* f_b1  = (const float*)d_in[11];
  const float* f_w2  = (const float*)d_in[12];
  const float* f_b2  = (const float*)d_in[13];
  const float* ta_wq = (const float*)d_in[14];
  const float* ta_wk = (const float*)d_in[15];
  const float* ta_wv = (const float*)d_in[16];
  const float* ta_wo = (const float*)d_in[17];
  const float* ta_bq = (const float*)d_in[18];
  const float* ta_bk = (const float*)d_in[19];
  const float* ta_bv = (const float*)d_in[20];
  const float* ta_bo = (const float*)d_in[21];
  const float* tr_w1 = (const float*)d_in[22];
  const float* tr_b1 = (const float*)d_in[23];
  const float* tr_w2 = (const float*)d_in[24];
  const float* tr_b2 = (const float*)d_in[25];
  const float* ps_w  = (const float*)d_in[26];
  const float* ps_b  = (const float*)d_in[27];
  const float* sp_w  = (const float*)d_in[28];
  const float* sp_b  = (const float*)d_in[29];
  const float* ln1_g = (const float*)d_in[30];
  const float* ln1_b = (const float*)d_in[31];
  const float* ln2_g = (const float*)d_in[32];
  const float* ln2_b = (const float*)d_in[33];
  const float* ln3_g = (const float*)d_in[34];
  const float* ln3_b = (const float*)d_in[35];
  const float* ln4_g = (const float*)d_in[36];
  const float* ln4_b = (const float*)d_in[37];

  char* ws = (char*)d_ws;
  int*    flags = (int*)   (ws + OFF_FLAGS);
  float*  bo_f  = (float*) (ws + OFF_BOF);
  float*  psum  = (float*) (ws + OFF_PSUM);
  float*  guid  = (float*) (ws + OFF_GUID);
  float*  Wff   = (float*) (ws + OFF_WF);
  ushort* qb    = (ushort*)(ws + OFF_Z1);
  ushort* kb    = (ushort*)(ws + OFF_Z2);
  ushort* vb    = (ushort*)(ws + OFF_Z3);
  ushort* attnb = (ushort*)(ws + OFF_Z4);
  float*  x0pre = (float*) (ws + OFF_Z1);
  float*  x1f   = (float*) (ws + OFF_Z3);
  ushort* ffnb  = (ushort*)(ws + OFF_M);
  ushort* mid   = (ushort*)(ws + OFF_M + (4u<<20));
  float*  x2pre = (float*) (ws + OFF_Z1);
  ushort* abf   = (ushort*)(ws + OFF_Z4);
  ushort* qtb   = (ushort*)(ws + OFF_Z3);
  ushort* Ubf   = (ushort*)(ws + OFF_M);
  float*  outb  = (float*)d_out;
  float*  out_h = outb + (out_size - 4096);

  static int attr_done = 0;
  if(!attr_done){
    hipFuncSetAttribute((const void*)scan_kernel,
                        hipFuncAttributeMaxDynamicSharedMemorySize, SCAN_DYN_LDS);
    attr_done = 1;
  }

  hipMemsetAsync(flags, 0, 8192, stream);

  // ===== parallel prefix =====
  gemm_kernel<1,0><<<512, 256, 0, stream>>>(x, sa_wq, 256, sa_bq, nullptr, nullptr, qb, 8192,256,256, 1.0f);
  gemm_kernel<1,0><<<512, 256, 0, stream>>>(x, sa_wk, 256, sa_bk, nullptr, nullptr, kb, 8192,256,256, 1.0f);
  gemm_kernel<1,0><<<512, 256, 0, stream>>>(x, sa_wv, 256, sa_bv, nullptr, nullptr, vb, 8192,256,256, 1.0f);
  attn_kernel<<<2048, 256, 0, stream>>>(qb, kb, vb, attnb);
  gemm_kernel<0,0><<<512, 256, 0, stream>>>(attnb, sa_wo, 256, sa_bo, x, x0pre, nullptr, 8192,256,256, 1.0f);
  ln_kernel<<<2048, 256, 0, stream>>>(x0pre, ln1_g, ln1_b, x1f, nullptr);
  guid_kernel<<<16, 256, 0, stream>>>(h0, sp_w, sp_b, guid);
  ffnin_kernel<<<1024, 256, 0, stream>>>(x1f, guid, ffnb);
  gemm_kernel<0,1><<<1024, 256, 0, stream>>>(ffnb, f_w1, 1024, f_b1, nullptr, nullptr, mid, 8192,512,256, 1.0f);
  gemm_kernel<0,0><<<512, 256, 0, stream>>>(mid, f_w2, 256, f_b2, x1f, x2pre, nullptr, 8192,256,512, 1.0f);
  gemm_kernel<0,1><<<1024, 256, 0, stream>>>(ffnb, f_w1 + 512, 1024, f_b1 + 512, nullptr, nullptr, mid, 8192,512,256, 1.0f);
  gemm_kernel<0,0><<<512, 256, 0, stream>>>(mid, f_w2 + (size_t)512*256, 256, nullptr, x2pre, x2pre, nullptr, 8192,256,512, 1.0f);
  ln_kernel<<<2048, 256, 0, stream>>>(x2pre, ln2_g, ln2_b, outb, nullptr);   // output 0 (f32)

  // ===== scan precompute (all GEMMs) =====
  gemm_kernel<1,0><<<512, 256, 0, stream>>>(outb, ps_w, 256, ps_b, outb, nullptr, abf, 8192,256,256, 0.3f);
  gemm_kernel<0,0><<<1024, 256, 0, stream>>>(abf, tr_w1, 512, tr_b1, nullptr, nullptr, Ubf, 8192,512,256, 1.0f);
  gemm_kernel<1,0><<<512, 256, 0, stream>>>(outb, ta_wq, 256, ta_bq, nullptr, nullptr, qtb, 8192,256,256, 1.0f);
  gemm_kernel<1,0><<<32, 256, 0, stream>>>(ta_wo, tr_w1 + (size_t)256*512, 512, nullptr, nullptr, Wff, nullptr, 256,512,256, 1.0f);
  bo_kernel<<<1, 512, 0, stream>>>(ta_bo, tr_w1, bo_f);

  // ===== sequential scan (persistent, one-hop, 64 blocks) =====
  scan_kernel<<<64, 512, SCAN_DYN_LDS, stream>>>(qtb, Ubf, Wff, bo_f, psum, flags,
                                                 ta_wk, ta_wv, ta_bk, ta_bv, tr_w2, tr_b2,
                                                 ln3_g, ln3_b, ln4_g, ln4_b, h0, out_h);
}

// Round 2
// 4265.903 us; speedup vs baseline: 3.4462x; 3.4462x over previous
//
#include <hip/hip_runtime.h>
#include <hip/hip_bf16.h>

typedef __bf16 bf16x8 __attribute__((ext_vector_type(8)));
typedef float f32x4 __attribute__((ext_vector_type(4)));

__device__ __forceinline__ float b2f(ushort u){
  union { uint u; float f; } x; x.u = ((uint)u) << 16; return x.f;
}
__device__ __forceinline__ ushort f2b(float f){
  union { float f; uint u; } x; x.f = f;
  uint r = x.u + 0x7fff + ((x.u >> 16) & 1);
  return (ushort)(r >> 16);
}
__device__ __forceinline__ uint pack_bf2(float a, float b){
  return (uint)f2b(a) | ((uint)f2b(b) << 16);
}
__device__ __forceinline__ float lo16(uint u){ union{uint a;float f;}x; x.a=u<<16; return x.f; }
__device__ __forceinline__ float hi16(uint u){ union{uint a;float f;}x; x.a=u&0xffff0000u; return x.f; }
__device__ __forceinline__ float gelu_exact(float v){
  return 0.5f * v * (1.0f + erff(v * 0.70710678118654752f));
}

// ---------------------------------------------------------------------------
// 64x64-tile MFMA bf16 GEMM (unchanged)
// ---------------------------------------------------------------------------
template<int AF32, int ACT>
__global__ __launch_bounds__(256) void gemm_kernel(
    const void* __restrict__ Av, const float* __restrict__ W, int ldw,
    const float* __restrict__ bias, const float* residf,
    float* Cf, ushort* Cb,
    int M, int N, int K, float scale)
{
  __shared__ __align__(16) ushort Al[64*40];
  __shared__ __align__(16) ushort Bl[64*40];
  const int nb = N >> 6;
  const int rb = blockIdx.x / nb, cb = blockIdx.x % nb;
  const int tid = threadIdx.x;
  const int w = tid >> 6, l = tid & 63;
  f32x4 acc[4];
#pragma unroll
  for(int i=0;i<4;i++) acc[i] = (f32x4){0.f,0.f,0.f,0.f};
  const int ar = tid >> 2, ai = (tid & 3) << 3;
  const int bk = tid >> 3, bn = (tid & 7) << 3;
  for(int kb = 0; kb < K; kb += 32){
    uint4 au;
    if(AF32){
      const float* Ap = (const float*)Av + (size_t)(rb*64 + ar)*K + kb + ai;
      float4 f0 = *(const float4*)Ap;
      float4 f1 = *(const float4*)(Ap + 4);
      au.x = pack_bf2(f0.x,f0.y); au.y = pack_bf2(f0.z,f0.w);
      au.z = pack_bf2(f1.x,f1.y); au.w = pack_bf2(f1.z,f1.w);
    } else {
      au = *(const uint4*)((const ushort*)Av + (size_t)(rb*64 + ar)*K + kb + ai);
    }
    const float* Wp = W + (size_t)(kb + bk)*ldw + cb*64 + bn;
    float4 w0 = *(const float4*)Wp;
    float4 w1 = *(const float4*)(Wp + 4);
    ushort bs[8];
    bs[0]=f2b(w0.x); bs[1]=f2b(w0.y); bs[2]=f2b(w0.z); bs[3]=f2b(w0.w);
    bs[4]=f2b(w1.x); bs[5]=f2b(w1.y); bs[6]=f2b(w1.z); bs[7]=f2b(w1.w);
    __syncthreads();
    *(uint4*)&Al[ar*40 + ai] = au;
#pragma unroll
    for(int i=0;i<8;i++) Bl[(bn+i)*40 + bk] = bs[i];
    __syncthreads();
    bf16x8 af = *(const bf16x8*)&Al[(w*16 + (l&15))*40 + (l>>4)*8];
#pragma unroll
    for(int c4=0;c4<4;c4++){
      bf16x8 bfv = *(const bf16x8*)&Bl[(c4*16 + (l&15))*40 + (l>>4)*8];
      acc[c4] = __builtin_amdgcn_mfma_f32_16x16x32_bf16(af, bfv, acc[c4], 0,0,0);
    }
  }
#pragma unroll
  for(int c4=0;c4<4;c4++){
#pragma unroll
    for(int r=0;r<4;r++){
      int row = rb*64 + w*16 + (l>>4)*4 + r;
      int col = cb*64 + c4*16 + (l&15);
      size_t idx = (size_t)row*N + col;
      float vv = acc[c4][r];
      if(bias) vv += bias[col];
      vv *= scale;
      if(residf) vv += residf[idx];
      if(ACT) vv = gelu_exact(vv);
      if(Cf) Cf[idx] = vv;
      if(Cb) Cb[idx] = f2b(vv);
    }
  }
}

// ---------------------------------------------------------------------------
// Causal self-attention (unchanged)
// ---------------------------------------------------------------------------
__global__ __launch_bounds__(256) void attn_kernel(const ushort* __restrict__ Q,
    const ushort* __restrict__ K, const ushort* __restrict__ V, ushort* __restrict__ O)
{
  __shared__ float s[16*520];
  __shared__ float kt[64*66];
  __shared__ float rowm[16], rowr[16], redx[256];
  const int bid = blockIdx.x;
  const int qb = bid & 31, h = (bid>>5)&3, b = bid>>7;
  const int tid = threadIdx.x;
  const int qi = tid >> 4, jj = tid & 15;
  const int qrow = qb*16 + qi;
  float qreg[64];
  {
    const ushort* qp = Q + ((size_t)(b*512 + qrow))*256 + h*64;
#pragma unroll
    for(int d=0; d<64; d++) qreg[d] = b2f(qp[d])*0.125f;
  }
  const int ntile = (qb*16 + 79) >> 6;
  for(int jt=0; jt<ntile; jt++){
    {
      int jr = tid >> 2, d0 = (tid & 3) << 4;
      const ushort* kp = K + ((size_t)(b*512 + jt*64 + jr))*256 + h*64 + d0;
#pragma unroll
      for(int i=0;i<16;i++) kt[jr*66 + d0 + i] = b2f(kp[i]);
    }
    __syncthreads();
#pragma unroll
    for(int jl=0;jl<4;jl++){
      int jloc = jj*4 + jl;
      int j = jt*64 + jloc;
      float a = 0.f;
#pragma unroll
      for(int d=0; d<64; d++) a += qreg[d]*kt[jloc*66 + d];
      s[qi*520 + j] = (j <= qrow) ? a : -1e30f;
    }
    __syncthreads();
  }
  const int nj = ntile*64;
  float m = -1e30f;
  for(int j=jj; j<nj; j+=16) m = fmaxf(m, s[qi*520 + j]);
  redx[jj*16 + qi] = m;
  __syncthreads();
  if(tid < 16){
    float mm = -1e30f;
#pragma unroll
    for(int k2=0;k2<16;k2++) mm = fmaxf(mm, redx[k2*16 + tid]);
    rowm[tid] = mm;
  }
  __syncthreads();
  float mrow = rowm[qi];
  float ssum = 0.f;
  for(int j=jj; j<nj; j+=16){
    float e = __expf(s[qi*520+j] - mrow);
    s[qi*520+j] = e; ssum += e;
  }
  redx[jj*16 + qi] = ssum;
  __syncthreads();
  if(tid < 16){
    float t2 = 0.f;
#pragma unroll
    for(int k2=0;k2<16;k2++) t2 += redx[k2*16 + tid];
    rowr[tid] = 1.0f/t2;
  }
  const int dd = jj;
  float acc4[4] = {0,0,0,0};
  for(int jt=0; jt<ntile; jt++){
    __syncthreads();
    {
      int jr = tid >> 2, d0 = (tid & 3) << 4;
      const ushort* vp = V + ((size_t)(b*512 + jt*64 + jr))*256 + h*64 + d0;
#pragma unroll
      for(int i=0;i<16;i++) kt[jr*66 + d0 + i] = b2f(vp[i]);
    }
    __syncthreads();
#pragma unroll
    for(int jl=0;jl<64;jl++){
      float p = s[qi*520 + jt*64 + jl];
#pragma unroll
      for(int i=0;i<4;i++) acc4[i] += p*kt[jl*66 + dd*4 + i];
    }
  }
  float rr = rowr[qi];
  ushort* op = O + ((size_t)(b*512 + qrow))*256 + h*64 + dd*4;
#pragma unroll
  for(int i=0;i<4;i++) op[i] = f2b(acc4[i]*rr);
}

// ---------------------------------------------------------------------------
// LayerNorm / small kernels (unchanged)
// ---------------------------------------------------------------------------
__global__ __launch_bounds__(256) void ln_kernel(const float* __restrict__ in,
    const float* __restrict__ g, const float* __restrict__ be,
    float* outf, ushort* outb)
{
  int row = blockIdx.x*4 + (threadIdx.x>>6);
  int lane = threadIdx.x & 63;
  size_t idx = (size_t)row*256 + lane*4;
  float4 v = *(const float4*)(in + idx);
  float s1 = v.x+v.y+v.z+v.w;
  float s2 = v.x*v.x + v.y*v.y + v.z*v.z + v.w*v.w;
#pragma unroll
  for(int off=32; off; off>>=1){ s1 += __shfl_xor(s1,off); s2 += __shfl_xor(s2,off); }
  float mu = s1*(1.f/256.f);
  float var = s2*(1.f/256.f) - mu*mu;
  float r = rsqrtf(var + 1e-5f);
  float vals[4] = {v.x,v.y,v.z,v.w};
  float4 o4; ushort4 ob;
  float* oo = (float*)&o4; ushort* obp = (ushort*)&ob;
#pragma unroll
  for(int i=0;i<4;i++){
    int d = lane*4 + i;
    float y = (vals[i]-mu)*r*g[d] + be[d];
    oo[i] = y; obp[i] = f2b(y);
  }
  if(outf) *(float4*)(outf+idx) = o4;
  if(outb) *(ushort4*)(outb+idx) = ob;
}

__global__ void guid_kernel(const float* __restrict__ h0, const float* __restrict__ spw,
                            const float* __restrict__ spb, float* __restrict__ guid)
{
  int b = blockIdx.x, c = threadIdx.x;
  float s = spb[c];
  for(int r=0;r<256;r++) s += h0[b*256+r]*spw[r*256+c];
  guid[b*256+c] = s;
}

__global__ void ffnin_kernel(const float* __restrict__ x1, const float* __restrict__ guid,
                             ushort* __restrict__ out)
{
  size_t base = ((size_t)blockIdx.x*256 + threadIdx.x)*8;
  int row = (int)(base >> 8); int bb = row >> 9; int c = (int)(base & 255);
  float4 v0 = *(const float4*)(x1 + base);
  float4 v1 = *(const float4*)(x1 + base + 4);
  const float* gp = guid + bb*256 + c;
  const float* xs = (const float*)&v0;
  ushort o[8];
#pragma unroll
  for(int i=0;i<4;i++) o[i] = f2b(xs[i] + 0.3f*gp[i]);
  const float* xs1 = (const float*)&v1;
#pragma unroll
  for(int i=0;i<4;i++) o[4+i] = f2b(xs1[i] + 0.3f*gp[4+i]);
  *(uint4*)(out + base) = *(uint4*)o;
}

__global__ void bo_kernel(const float* __restrict__ ta_bo, const float* __restrict__ tr_w1,
                          float* __restrict__ bo_f)
{
  int c = threadIdx.x;
  float s = 0.f;
  for(int m=0;m<256;m++) s += ta_bo[m]*tr_w1[(size_t)(256+m)*512 + c];
  bo_f[c] = s;
}

// ---------------------------------------------------------------------------
// Persistent scan. 128 blocks x 512 threads — PROVEN comm topology (X/Y two-hop,
// all peers same-XCD at this launch geometry, L2-only traffic).
// role = bid>>4: 0..3 = X (attention head), 4..7 = Y (MLP quarter-shard).
//
// NEW in this round: X computes the score dot-products AND the exp-weighted
// V-sums for rows <= t-1 in the SHADOW of the Y-wait (flash-style per-group
// online softmax: 16 groups of 32 rows, per-group max/sum + partial ctx,
// rescaled at finalize). On the critical chain only remain: kv matvec (row
// t-1) + last-row score (from k regs via shuffle) + B1 + tiny 16-group
// combine in wave0. X barriers: 4 -> 2 per step; cbuf publishes much earlier.
// Shadow state double-buffered by parity (red/mG/sG).
// Flags: [0..63] fastX(b*4+hd)=t, [64..127] fastY(b*4+ish)=t+1,
//        [128..191] shadowX, [192..255] shadowY, [256..383] xcc table.
// ---------------------------------------------------------------------------
__global__ __launch_bounds__(512, 1) void scan_kernel(
    const ushort* __restrict__ qtb, const ushort* __restrict__ Ubf,
    const float* __restrict__ Wf, const float* __restrict__ bo_f,
    float* cbuf, float* dbuf, int* flags,
    const float* __restrict__ ta_wk, const float* __restrict__ ta_wv,
    const float* __restrict__ ta_bk, const float* __restrict__ ta_bv,
    const float* __restrict__ tr_w2, const float* __restrict__ tr_b2,
    const float* __restrict__ ln3_g, const float* __restrict__ ln3_b,
    const float* __restrict__ ln4_g, const float* __restrict__ ln4_b,
    const float* __restrict__ h0, float* __restrict__ out_h)
{
  __shared__ __align__(16) float red[2][1024];
  __shared__ float pbuf[512];
  __shared__ __align__(16) float hbuf[256];
  __shared__ float ctxL[256];
  __shared__ float qbufS[2][64];
  __shared__ float mG[2][16], sG[2][16];
  __shared__ float sLastP[4];
  __shared__ float glbuf[128];
  __shared__ int cp_same[4];
  extern __shared__ __align__(16) ushort dynL[];
  ushort* kcL = dynL;             // [512][66] u16
  ushort* vcL = dynL + 512*66;    // [512][66] u16

  const int tid = threadIdx.x;
  const int bid = blockIdx.x;
  const int b = bid & 15;
  const int role = bid >> 4;

  if(role < 4){   // zero k/v caches (safety; tail never read by construction)
    for(int i = tid; i < 512*66; i += 512){ kcL[i] = 0; vcL[i] = 0; }
  }

  // ---- one-time XCD handshake ----
  int myxcc;
  asm volatile("s_getreg_b32 %0, hwreg(HW_REG_XCC_ID)" : "=s"(myxcc));
  if(tid == 0)
    __hip_atomic_store(&flags[256 + bid], myxcc + 1, __ATOMIC_RELEASE, __HIP_MEMORY_SCOPE_AGENT);
  if(tid < 4){
    int cbid = (role < 4) ? (64 + tid*16 + b) : (tid*16 + b);
    int v;
    while((v = __hip_atomic_load(&flags[256 + cbid], __ATOMIC_ACQUIRE, __HIP_MEMORY_SCOPE_AGENT)) == 0)
      __builtin_amdgcn_s_sleep(8);
    cp_same[tid] = ((v - 1) == myxcc);
  }
  __syncthreads();
  const int anyrem = !(cp_same[0] && cp_same[1] && cp_same[2] && cp_same[3]);

  if(role < 4){
    // ================= X: attention head hd =================
    const int hd = role;
    const int bh = b*4 + hd;
    // matvec: thread = out*4 + s; out<64 -> k col, out>=64 -> v col.
    const int out = tid >> 2, sX = tid & 3;
    const int kvSel = out >> 6, colX = out & 63;
    const float* WX = kvSel ? ta_wv : ta_wk;
    uint wp[32];
#pragma unroll
    for(int i=0;i<32;i++){
      int r0 = 8*i + 2*sX;
      wp[i] = pack_bf2(WX[(size_t)r0*256 + hd*64 + colX],
                       WX[(size_t)(r0+1)*256 + hd*64 + colX]);
    }
    const float pbX = kvSel ? ta_bv[hd*64 + colX] : ta_bk[hd*64 + colX];
    // wave0 LN state (lane l owns cols 4l..4l+3)
    float h4[4], b2r4[4], g34[4], b34[4];
    if(tid < 64){
#pragma unroll
      for(int c=0;c<4;c++){
        int d = 4*tid + c;
        h4[c] = h0[b*256 + d]; b2r4[c] = tr_b2[d]; g34[c] = ln3_g[d]; b34[c] = ln3_b[d];
      }
      *(float4*)&hbuf[4*tid] = *(float4*)h4;
    }
    // shadow row mapping: threads 64..511 -> rows 0..447; wave0 -> rows 448..511
    const int j_sh = (tid >= 64) ? (tid - 64) : (448 + tid);
    const int gsh = j_sh >> 5;       // group 0..15 (32 rows each)
    const int lsh = tid & 31;        // lane within group (d-pair owner)
    __syncthreads();

    // q prefetch (row 1) — wave 7 stages q into LDS each step (double-buffered)
    ushort qpre = 0;
    if(tid >= 448) qpre = qtb[((size_t)(b*512 + 1))*256 + hd*64 + (tid - 448)];

#pragma clang loop unroll(disable)
    for(int t=0;t<512;t++){
      // stage q_{t+1} into slot (t+1)&1; issue q_{t+2} load
      if(tid >= 448){
        qbufS[(t+1)&1][tid-448] = b2f(qpre)*0.125f;
        int tq = (t+2 < 512) ? (t+2) : 511;
        qpre = qtb[((size_t)(b*512 + tq))*256 + hd*64 + (tid - 448)];
      }
      if(t > 0){
        // [K] k/v row t-1 from h_t (in hbuf); last-row score partial via shuffle
        float acc = 0.f;
#pragma unroll
        for(int i=0;i<32;i++){
          int r0 = 8*i + 2*sX;
          acc += hbuf[r0]*lo16(wp[i]) + hbuf[r0+1]*hi16(wp[i]);
        }
        acc += __shfl_xor(acc, 1);
        acc += __shfl_xor(acc, 2);
        float kf = acc + pbX;
        if(sX == 0){
          ushort u = f2b(kf);
          if(kvSel == 0) kcL[(t-1)*66 + colX] = u;
          else           vcL[(t-1)*66 + colX] = u;
        }
        // s_last = q_t . k_{t-1}: products live in lanes with sX==0, kvSel==0
        float pv = (kvSel == 0 && sX == 0) ? qbufS[t&1][colX]*kf : 0.f;
        pv += __shfl_xor(pv, 4);
        pv += __shfl_xor(pv, 8);
        pv += __shfl_xor(pv, 16);
        pv += __shfl_xor(pv, 32);
        if(tid < 256 && (tid & 63) == 0) sLastP[tid >> 6] = pv;
        __syncthreads();                                   // B1
        // [F] wave0 finalize: combine 16 shadow groups + last row, store cbuf
        if(tid < 64){
          const int par = t & 1;
          float sl = (sLastP[0] + sLastP[1]) + (sLastP[2] + sLastP[3]);
          float m = sl;
#pragma unroll
          for(int g=0; g<16; g++) m = fmaxf(m, mG[par][g]);
          float el = __expf(sl - m);
          float Z = el;
          float num = el * b2f(vcL[(t-1)*66 + tid]);
#pragma unroll
          for(int g=0; g<16; g++){
            float scl = __expf(mG[par][g] - m);
            Z   += sG[par][g]*scl;
            num += red[par][g*64 + tid]*scl;
          }
          cbuf[b*256 + hd*64 + tid] = num / Z;
          asm volatile("s_waitcnt vmcnt(0)" ::: "memory");
          if(tid == 0){
            *(volatile int*)&flags[bh] = t;
            if(anyrem)
              __hip_atomic_store(&flags[128 + bh], t, __ATOMIC_RELEASE, __HIP_MEMORY_SCOPE_AGENT);
          }
        }
      } // t>0

      // [S] shadow for step t+1: rows j_sh <= t-1, write parity (t+1)&1.
      //     Runs while Y processes ctx_t (wave0's slice is empty until t>448).
      {
        const int par = (t+1)&1;
        float s = -3.0e38f;
        if(j_sh < t){
          const uint* kr = (const uint*)(kcL + j_sh*66);
          const float* qS = qbufS[par];
          float a = 0.f;
#pragma unroll
          for(int w=0; w<32; w++){
            uint kk = kr[w];
            a += qS[2*w]*lo16(kk) + qS[2*w+1]*hi16(kk);
          }
          s = a;
        }
        // 32-lane (group) reduce: offsets stay within half-wave
        float gm = s;
#pragma unroll
        for(int off=16; off; off>>=1) gm = fmaxf(gm, __shfl_xor(gm, off));
        float e = (j_sh < t) ? __expf(s - gm) : 0.f;
        pbuf[j_sh] = e;
        float gs = e;
#pragma unroll
        for(int off=16; off; off>>=1) gs += __shfl_xor(gs, off);
        if(lsh == 0){ mG[par][gsh] = gm; sG[par][gsh] = gs; }
        // partial ctx for this group: lane owns d-pair (2lsh, 2lsh+1)
        int nn = t - gsh*32; nn = nn < 0 ? 0 : (nn > 32 ? 32 : nn);
        float a0 = 0.f, a1 = 0.f;
        const uint* vbase = (const uint*)vcL;
#pragma unroll 4
        for(int i=0;i<nn;i++){
          int j2 = gsh*32 + i;
          uint vv = vbase[j2*33 + lsh];
          float p = pbuf[j2];
          a0 += p*lo16(vv); a1 += p*hi16(vv);
        }
        float2 pr; pr.x = a0; pr.y = a1;
        *(float2*)&red[par][gsh*64 + 2*lsh] = pr;
      }

      // wave0: poll 4 Y deltas, then single-wave LN3
      if(tid < 4){
        if(cp_same[tid]){
          while(*(volatile int*)&flags[64 + b*4 + tid] < t+1) __builtin_amdgcn_s_sleep(1);
        } else {
          while(__hip_atomic_load(&flags[192 + b*4 + tid], __ATOMIC_RELAXED, __HIP_MEMORY_SCOPE_AGENT) < t+1)
            __builtin_amdgcn_s_sleep(2);
        }
      }
      if(tid < 64){
        if(anyrem) __builtin_amdgcn_fence(__ATOMIC_ACQUIRE, "agent");
        float ds[4] = {0.f,0.f,0.f,0.f};
#pragma unroll
        for(int i=0;i<4;i++){
#pragma unroll
          for(int c=0;c<4;c++)
            ds[c] += *(volatile float*)&dbuf[(b*4+i)*256 + 4*tid + c];
        }
        float v4[4]; float s1 = 0.f, s2 = 0.f;
#pragma unroll
        for(int c=0;c<4;c++){
          v4[c] = h4[c] + 0.5f*(ds[c] + b2r4[c]);
          s1 += v4[c]; s2 += v4[c]*v4[c];
        }
#pragma unroll
        for(int off=32; off; off>>=1){ s1 += __shfl_xor(s1,off); s2 += __shfl_xor(s2,off); }
        float mu = s1*(1.f/256.f);
        float qq = s2*(1.f/256.f) - mu*mu;
        float rstd = rsqrtf(qq + 1e-5f);
#pragma unroll
        for(int c=0;c<4;c++) h4[c] = (v4[c]-mu)*rstd*g34[c] + b34[c];
        *(float4*)&hbuf[4*tid] = *(float4*)h4;
      }
      __syncthreads();                                     // B_LN
    } // t loop

    if(hd == 0 && tid < 64){
      float s1 = 0.f, s2 = 0.f;
#pragma unroll
      for(int c=0;c<4;c++){ s1 += h4[c]; s2 += h4[c]*h4[c]; }
#pragma unroll
      for(int off=32; off; off>>=1){ s1 += __shfl_xor(s1,off); s2 += __shfl_xor(s2,off); }
      float mu = s1*(1.f/256.f);
      float qq = s2*(1.f/256.f) - mu*mu;
      float rstd = rsqrtf(qq + 1e-5f);
#pragma unroll
      for(int c=0;c<4;c++){
        int d = 4*tid + c;
        out_h[b*256 + d] = (h4[c]-mu)*rstd*ln4_g[d] + ln4_b[d];
      }
    }
  } else {
    // ================= Y: MLP quarter-shard ish (128 hidden) =================
    const int ish = role - 4;
    // Wf matvec: thread = hid*4 + sY (hid<128)
    const int hid = tid >> 2, sY = tid & 3;
    const int colY = ish*128 + hid;
    uint wfp[32];
#pragma unroll
    for(int i=0;i<32;i++){
      int r0 = 8*i + 2*sY;
      wfp[i] = pack_bf2(Wf[(size_t)r0*512 + colY], Wf[(size_t)(r0+1)*512 + colY]);
    }
    // w2 matvec: thread = dcol*2 + s2 (dcol<256), local hidden rows 4i+2*s2
    const int dcol = tid >> 1, s2 = tid & 1;
    uint w2p[32];
#pragma unroll
    for(int i=0;i<32;i++){
      int r0 = ish*128 + 4*i + 2*s2;
      w2p[i] = pack_bf2(tr_w2[(size_t)r0*256 + dcol], tr_w2[(size_t)(r0+1)*256 + dcol]);
    }
    const float borr = (sY==0) ? bo_f[colY] : 0.f;
    __syncthreads();

#pragma clang loop unroll(disable)
    for(int t=0;t<512;t++){
      ushort uvs = 0;
      if(sY == 0) uvs = Ubf[((size_t)(b*512 + t))*512 + colY];
      if(t > 0){
        if(tid < 256){
          int q = tid >> 6;
          if(cp_same[q]){
            while(*(volatile int*)&flags[b*4 + q] < t) __builtin_amdgcn_s_sleep(1);
          } else {
            while(__hip_atomic_load(&flags[128 + b*4 + q], __ATOMIC_RELAXED, __HIP_MEMORY_SCOPE_AGENT) < t)
              __builtin_amdgcn_s_sleep(2);
          }
        }
        if(anyrem) __builtin_amdgcn_fence(__ATOMIC_ACQUIRE, "agent");
        if(tid < 256) ctxL[tid] = *(volatile float*)&cbuf[b*256 + tid];
      }
      __syncthreads();                                     // B1
      float accf = 0.f;
      if(t > 0){
#pragma unroll
        for(int i=0;i<32;i++){
          int r0 = 8*i + 2*sY;
          accf += ctxL[r0]*lo16(wfp[i]) + ctxL[r0+1]*hi16(wfp[i]);
        }
        accf += __shfl_xor(accf, 1);
        accf += __shfl_xor(accf, 2);
      }
      if(sY == 0){
        float g1 = b2f(uvs) + ((t>0) ? (borr + accf) : 0.f);
        glbuf[hid] = gelu_exact(g1);
      }
      __syncthreads();                                     // B2
      {
        float dp = 0.f;
#pragma unroll
        for(int i=0;i<32;i++){
          int r0 = 4*i + 2*s2;
          dp += glbuf[r0]*lo16(w2p[i]) + glbuf[r0+1]*hi16(w2p[i]);
        }
        dp += __shfl_xor(dp, 1);
        if(s2 == 0) dbuf[(b*4+ish)*256 + dcol] = dp;
      }
      asm volatile("s_waitcnt vmcnt(0)" ::: "memory");
      __syncthreads();                                     // B3
      if(tid == 0){
        *(volatile int*)&flags[64 + b*4 + ish] = t+1;
        if(anyrem)
          __hip_atomic_store(&flags[192 + b*4 + ish], t+1, __ATOMIC_RELEASE, __HIP_MEMORY_SCOPE_AGENT);
      }
    }
  }
}

// ---------------------------------------------------------------------------
// Workspace layout (bytes). TOTAL = 29 MiB.
// ---------------------------------------------------------------------------
#define OFF_FLAGS ((size_t)0)
#define OFF_BOF   ((size_t)2048)
#define OFF_CBUF  ((size_t)4096)
#define OFF_DBUF  ((size_t)20480)
#define OFF_GUID  ((size_t)86016)
#define OFF_WF    ((size_t)131072)
#define OFF_Z1    ((size_t)(1u<<20))
#define OFF_Z2    ((size_t)(5u<<20))
#define OFF_Z3    ((size_t)(9u<<20))
#define OFF_Z4    ((size_t)(13u<<20))
#define OFF_M     ((size_t)(17u<<20))

#define SCAN_DYN_LDS (512*66*2*2)   // 135168 B

extern "C" void kernel_launch(void* const* d_in, const int* in_sizes, int n_in,
                              void* d_out, int out_size, void* d_ws, size_t ws_size,
                              hipStream_t stream)
{
  const float* x     = (const float*)d_in[0];
  const float* h0    = (const float*)d_in[1];
  const float* sa_wq = (const float*)d_in[2];
  const float* sa_wk = (const float*)d_in[3];
  const float* sa_wv = (const float*)d_in[4];
  const float* sa_wo = (const float*)d_in[5];
  const float* sa_bq = (const float*)d_in[6];
  const float* sa_bk = (const float*)d_in[7];
  const float* sa_bv = (const float*)d_in[8];
  const float* sa_bo = (const float*)d_in[9];
  const float* f_w1  = (const float*)d_in[10];
  const float* f_b1  = (const float*)d_in[11];
  const float* f_w2  = (const float*)d_in[12];
  const float* f_b2  = (const float*)d_in[13];
  const float* ta_wq = (const float*)d_in[14];
  const float* ta_wk = (const float*)d_in[15];
  const float* ta_wv = (const float*)d_in[16];
  const float* ta_wo = (const float*)d_in[17];
  const float* ta_bq = (const float*)d_in[18];
  const float* ta_bk = (const float*)d_in[19];
  const float* ta_bv = (const float*)d_in[20];
  const float* ta_bo = (const float*)d_in[21];
  const float* tr_w1 = (const float*)d_in[22];
  const float* tr_b1 = (const float*)d_in[23];
  const float* tr_w2 = (const float*)d_in[24];
  const float* tr_b2 = (const float*)d_in[25];
  const float* ps_w  = (const float*)d_in[26];
  const float* ps_b  = (const float*)d_in[27];
  const float* sp_w  = (const float*)d_in[28];
  const float* sp_b  = (const float*)d_in[29];
  const float* ln1_g = (const float*)d_in[30];
  const float* ln1_b = (const float*)d_in[31];
  const float* ln2_g = (const float*)d_in[32];
  const float* ln2_b = (const float*)d_in[33];
  const float* ln3_g = (const float*)d_in[34];
  const float* ln3_b = (const float*)d_in[35];
  const float* ln4_g = (const float*)d_in[36];
  const float* ln4_b = (const float*)d_in[37];

  char* ws = (char*)d_ws;
  int*    flags = (int*)   (ws + OFF_FLAGS);
  float*  bo_f  = (float*) (ws + OFF_BOF);
  float*  cbuf  = (float*) (ws + OFF_CBUF);
  float*  dbuf  = (float*) (ws + OFF_DBUF);
  float*  guid  = (float*) (ws + OFF_GUID);
  float*  Wff   = (float*) (ws + OFF_WF);
  ushort* qb    = (ushort*)(ws + OFF_Z1);
  ushort* kb    = (ushort*)(ws + OFF_Z2);
  ushort* vb    = (ushort*)(ws + OFF_Z3);
  ushort* attnb = (ushort*)(ws + OFF_Z4);
  float*  x0pre = (float*) (ws + OFF_Z1);
  float*  x1f   = (float*) (ws + OFF_Z3);
  ushort* ffnb  = (ushort*)(ws + OFF_M);
  ushort* mid   = (ushort*)(ws + OFF_M + (4u<<20));
  float*  x2pre = (float*) (ws + OFF_Z1);
  ushort* abf   = (ushort*)(ws + OFF_Z4);
  ushort* qtb   = (ushort*)(ws + OFF_Z3);
  ushort* Ubf   = (ushort*)(ws + OFF_M);
  float*  outb  = (float*)d_out;
  float*  out_h = outb + (out_size - 4096);

  static int attr_done = 0;
  if(!attr_done){
    hipFuncSetAttribute((const void*)scan_kernel,
                        hipFuncAttributeMaxDynamicSharedMemorySize, SCAN_DYN_LDS);
    attr_done = 1;
  }

  hipMemsetAsync(flags, 0, 2048, stream);

  // ===== parallel prefix =====
  gemm_kernel<1,0><<<512, 256, 0, stream>>>(x, sa_wq, 256, sa_bq, nullptr, nullptr, qb, 8192,256,256, 1.0f);
  gemm_kernel<1,0><<<512, 256, 0, stream>>>(x, sa_wk, 256, sa_bk, nullptr, nullptr, kb, 8192,256,256, 1.0f);
  gemm_kernel<1,0><<<512, 256, 0, stream>>>(x, sa_wv, 256, sa_bv, nullptr, nullptr, vb, 8192,256,256, 1.0f);
  attn_kernel<<<2048, 256, 0, stream>>>(qb, kb, vb, attnb);
  gemm_kernel<0,0><<<512, 256, 0, stream>>>(attnb, sa_wo, 256, sa_bo, x, x0pre, nullptr, 8192,256,256, 1.0f);
  ln_kernel<<<2048, 256, 0, stream>>>(x0pre, ln1_g, ln1_b, x1f, nullptr);
  guid_kernel<<<16, 256, 0, stream>>>(h0, sp_w, sp_b, guid);
  ffnin_kernel<<<1024, 256, 0, stream>>>(x1f, guid, ffnb);
  gemm_kernel<0,1><<<1024, 256, 0, stream>>>(ffnb, f_w1, 1024, f_b1, nullptr, nullptr, mid, 8192,512,256, 1.0f);
  gemm_kernel<0,0><<<512, 256, 0, stream>>>(mid, f_w2, 256, f_b2, x1f, x2pre, nullptr, 8192,256,512, 1.0f);
  gemm_kernel<0,1><<<1024, 256, 0, stream>>>(ffnb, f_w1 + 512, 1024, f_b1 + 512, nullptr, nullptr, mid, 8192,512,256, 1.0f);
  gemm_kernel<0,0><<<512, 256, 0, stream>>>(mid, f_w2 + (size_t)512*256, 256, nullptr, x2pre, x2pre, nullptr, 8192,256,512, 1.0f);
  ln_kernel<<<2048, 256, 0, stream>>>(x2pre, ln2_g, ln2_b, outb, nullptr);   // output 0 (f32)

  // ===== scan precompute (all GEMMs) =====
  gemm_kernel<1,0><<<512, 256, 0, stream>>>(outb, ps_w, 256, ps_b, outb, nullptr, abf, 8192,256,256, 0.3f);
  gemm_kernel<0,0><<<1024, 256, 0, stream>>>(abf, tr_w1, 512, tr_b1, nullptr, nullptr, Ubf, 8192,512,256, 1.0f);
  gemm_kernel<1,0><<<512, 256, 0, stream>>>(outb, ta_wq, 256, ta_bq, nullptr, nullptr, qtb, 8192,256,256, 1.0f);
  gemm_kernel<1,0><<<32, 256, 0, stream>>>(ta_wo, tr_w1 + (size_t)256*512, 512, nullptr, nullptr, Wff, nullptr, 256,512,256, 1.0f);
  bo_kernel<<<1, 512, 0, stream>>>(ta_bo, tr_w1, bo_f);

  // ===== sequential scan (persistent, LDS k/v caches, shadowed scores) =====
  scan_kernel<<<128, 512, SCAN_DYN_LDS, stream>>>(qtb, Ubf, Wff, bo_f, cbuf, dbuf, flags,
                                                  ta_wk, ta_wv, ta_bk, ta_bv, tr_w2, tr_b2,
                                                  ln3_g, ln3_b, ln4_g, ln4_b, h0, out_h);
}

// Round 3
// 3525.557 us; speedup vs baseline: 4.1699x; 1.2100x over previous
//
#include <hip/hip_runtime.h>
#include <hip/hip_bf16.h>

typedef __bf16 bf16x8 __attribute__((ext_vector_type(8)));
typedef float f32x4 __attribute__((ext_vector_type(4)));

__device__ __forceinline__ float b2f(ushort u){
  union { uint u; float f; } x; x.u = ((uint)u) << 16; return x.f;
}
__device__ __forceinline__ ushort f2b(float f){
  union { float f; uint u; } x; x.f = f;
  uint r = x.u + 0x7fff + ((x.u >> 16) & 1);
  return (ushort)(r >> 16);
}
__device__ __forceinline__ uint pack_bf2(float a, float b){
  return (uint)f2b(a) | ((uint)f2b(b) << 16);
}
__device__ __forceinline__ float lo16(uint u){ union{uint a;float f;}x; x.a=u<<16; return x.f; }
__device__ __forceinline__ float hi16(uint u){ union{uint a;float f;}x; x.a=u&0xffff0000u; return x.f; }
__device__ __forceinline__ float gelu_exact(float v){
  return 0.5f * v * (1.0f + erff(v * 0.70710678118654752f));
}

// ---------------------------------------------------------------------------
// 64x64-tile MFMA bf16 GEMM (unchanged)
// ---------------------------------------------------------------------------
template<int AF32, int ACT>
__global__ __launch_bounds__(256) void gemm_kernel(
    const void* __restrict__ Av, const float* __restrict__ W, int ldw,
    const float* __restrict__ bias, const float* residf,
    float* Cf, ushort* Cb,
    int M, int N, int K, float scale)
{
  __shared__ __align__(16) ushort Al[64*40];
  __shared__ __align__(16) ushort Bl[64*40];
  const int nb = N >> 6;
  const int rb = blockIdx.x / nb, cb = blockIdx.x % nb;
  const int tid = threadIdx.x;
  const int w = tid >> 6, l = tid & 63;
  f32x4 acc[4];
#pragma unroll
  for(int i=0;i<4;i++) acc[i] = (f32x4){0.f,0.f,0.f,0.f};
  const int ar = tid >> 2, ai = (tid & 3) << 3;
  const int bk = tid >> 3, bn = (tid & 7) << 3;
  for(int kb = 0; kb < K; kb += 32){
    uint4 au;
    if(AF32){
      const float* Ap = (const float*)Av + (size_t)(rb*64 + ar)*K + kb + ai;
      float4 f0 = *(const float4*)Ap;
      float4 f1 = *(const float4*)(Ap + 4);
      au.x = pack_bf2(f0.x,f0.y); au.y = pack_bf2(f0.z,f0.w);
      au.z = pack_bf2(f1.x,f1.y); au.w = pack_bf2(f1.z,f1.w);
    } else {
      au = *(const uint4*)((const ushort*)Av + (size_t)(rb*64 + ar)*K + kb + ai);
    }
    const float* Wp = W + (size_t)(kb + bk)*ldw + cb*64 + bn;
    float4 w0 = *(const float4*)Wp;
    float4 w1 = *(const float4*)(Wp + 4);
    ushort bs[8];
    bs[0]=f2b(w0.x); bs[1]=f2b(w0.y); bs[2]=f2b(w0.z); bs[3]=f2b(w0.w);
    bs[4]=f2b(w1.x); bs[5]=f2b(w1.y); bs[6]=f2b(w1.z); bs[7]=f2b(w1.w);
    __syncthreads();
    *(uint4*)&Al[ar*40 + ai] = au;
#pragma unroll
    for(int i=0;i<8;i++) Bl[(bn+i)*40 + bk] = bs[i];
    __syncthreads();
    bf16x8 af = *(const bf16x8*)&Al[(w*16 + (l&15))*40 + (l>>4)*8];
#pragma unroll
    for(int c4=0;c4<4;c4++){
      bf16x8 bfv = *(const bf16x8*)&Bl[(c4*16 + (l&15))*40 + (l>>4)*8];
      acc[c4] = __builtin_amdgcn_mfma_f32_16x16x32_bf16(af, bfv, acc[c4], 0,0,0);
    }
  }
#pragma unroll
  for(int c4=0;c4<4;c4++){
#pragma unroll
    for(int r=0;r<4;r++){
      int row = rb*64 + w*16 + (l>>4)*4 + r;
      int col = cb*64 + c4*16 + (l&15);
      size_t idx = (size_t)row*N + col;
      float vv = acc[c4][r];
      if(bias) vv += bias[col];
      vv *= scale;
      if(residf) vv += residf[idx];
      if(ACT) vv = gelu_exact(vv);
      if(Cf) Cf[idx] = vv;
      if(Cb) Cb[idx] = f2b(vv);
    }
  }
}

// ---------------------------------------------------------------------------
// Causal self-attention (unchanged)
// ---------------------------------------------------------------------------
__global__ __launch_bounds__(256) void attn_kernel(const ushort* __restrict__ Q,
    const ushort* __restrict__ K, const ushort* __restrict__ V, ushort* __restrict__ O)
{
  __shared__ float s[16*520];
  __shared__ float kt[64*66];
  __shared__ float rowm[16], rowr[16], redx[256];
  const int bid = blockIdx.x;
  const int qb = bid & 31, h = (bid>>5)&3, b = bid>>7;
  const int tid = threadIdx.x;
  const int qi = tid >> 4, jj = tid & 15;
  const int qrow = qb*16 + qi;
  float qreg[64];
  {
    const ushort* qp = Q + ((size_t)(b*512 + qrow))*256 + h*64;
#pragma unroll
    for(int d=0; d<64; d++) qreg[d] = b2f(qp[d])*0.125f;
  }
  const int ntile = (qb*16 + 79) >> 6;
  for(int jt=0; jt<ntile; jt++){
    {
      int jr = tid >> 2, d0 = (tid & 3) << 4;
      const ushort* kp = K + ((size_t)(b*512 + jt*64 + jr))*256 + h*64 + d0;
#pragma unroll
      for(int i=0;i<16;i++) kt[jr*66 + d0 + i] = b2f(kp[i]);
    }
    __syncthreads();
#pragma unroll
    for(int jl=0;jl<4;jl++){
      int jloc = jj*4 + jl;
      int j = jt*64 + jloc;
      float a = 0.f;
#pragma unroll
      for(int d=0; d<64; d++) a += qreg[d]*kt[jloc*66 + d];
      s[qi*520 + j] = (j <= qrow) ? a : -1e30f;
    }
    __syncthreads();
  }
  const int nj = ntile*64;
  float m = -1e30f;
  for(int j=jj; j<nj; j+=16) m = fmaxf(m, s[qi*520 + j]);
  redx[jj*16 + qi] = m;
  __syncthreads();
  if(tid < 16){
    float mm = -1e30f;
#pragma unroll
    for(int k2=0;k2<16;k2++) mm = fmaxf(mm, redx[k2*16 + tid]);
    rowm[tid] = mm;
  }
  __syncthreads();
  float mrow = rowm[qi];
  float ssum = 0.f;
  for(int j=jj; j<nj; j+=16){
    float e = __expf(s[qi*520+j] - mrow);
    s[qi*520+j] = e; ssum += e;
  }
  redx[jj*16 + qi] = ssum;
  __syncthreads();
  if(tid < 16){
    float t2 = 0.f;
#pragma unroll
    for(int k2=0;k2<16;k2++) t2 += redx[k2*16 + tid];
    rowr[tid] = 1.0f/t2;
  }
  const int dd = jj;
  float acc4[4] = {0,0,0,0};
  for(int jt=0; jt<ntile; jt++){
    __syncthreads();
    {
      int jr = tid >> 2, d0 = (tid & 3) << 4;
      const ushort* vp = V + ((size_t)(b*512 + jt*64 + jr))*256 + h*64 + d0;
#pragma unroll
      for(int i=0;i<16;i++) kt[jr*66 + d0 + i] = b2f(vp[i]);
    }
    __syncthreads();
#pragma unroll
    for(int jl=0;jl<64;jl++){
      float p = s[qi*520 + jt*64 + jl];
#pragma unroll
      for(int i=0;i<4;i++) acc4[i] += p*kt[jl*66 + dd*4 + i];
    }
  }
  float rr = rowr[qi];
  ushort* op = O + ((size_t)(b*512 + qrow))*256 + h*64 + dd*4;
#pragma unroll
  for(int i=0;i<4;i++) op[i] = f2b(acc4[i]*rr);
}

// ---------------------------------------------------------------------------
// LayerNorm / small kernels (unchanged)
// ---------------------------------------------------------------------------
__global__ __launch_bounds__(256) void ln_kernel(const float* __restrict__ in,
    const float* __restrict__ g, const float* __restrict__ be,
    float* outf, ushort* outb)
{
  int row = blockIdx.x*4 + (threadIdx.x>>6);
  int lane = threadIdx.x & 63;
  size_t idx = (size_t)row*256 + lane*4;
  float4 v = *(const float4*)(in + idx);
  float s1 = v.x+v.y+v.z+v.w;
  float s2 = v.x*v.x + v.y*v.y + v.z*v.z + v.w*v.w;
#pragma unroll
  for(int off=32; off; off>>=1){ s1 += __shfl_xor(s1,off); s2 += __shfl_xor(s2,off); }
  float mu = s1*(1.f/256.f);
  float var = s2*(1.f/256.f) - mu*mu;
  float r = rsqrtf(var + 1e-5f);
  float vals[4] = {v.x,v.y,v.z,v.w};
  float4 o4; ushort4 ob;
  float* oo = (float*)&o4; ushort* obp = (ushort*)&ob;
#pragma unroll
  for(int i=0;i<4;i++){
    int d = lane*4 + i;
    float y = (vals[i]-mu)*r*g[d] + be[d];
    oo[i] = y; obp[i] = f2b(y);
  }
  if(outf) *(float4*)(outf+idx) = o4;
  if(outb) *(ushort4*)(outb+idx) = ob;
}

__global__ void guid_kernel(const float* __restrict__ h0, const float* __restrict__ spw,
                            const float* __restrict__ spb, float* __restrict__ guid)
{
  int b = blockIdx.x, c = threadIdx.x;
  float s = spb[c];
  for(int r=0;r<256;r++) s += h0[b*256+r]*spw[r*256+c];
  guid[b*256+c] = s;
}

__global__ void ffnin_kernel(const float* __restrict__ x1, const float* __restrict__ guid,
                             ushort* __restrict__ out)
{
  size_t base = ((size_t)blockIdx.x*256 + threadIdx.x)*8;
  int row = (int)(base >> 8); int bb = row >> 9; int c = (int)(base & 255);
  float4 v0 = *(const float4*)(x1 + base);
  float4 v1 = *(const float4*)(x1 + base + 4);
  const float* gp = guid + bb*256 + c;
  const float* xs = (const float*)&v0;
  ushort o[8];
#pragma unroll
  for(int i=0;i<4;i++) o[i] = f2b(xs[i] + 0.3f*gp[i]);
  const float* xs1 = (const float*)&v1;
#pragma unroll
  for(int i=0;i<4;i++) o[4+i] = f2b(xs1[i] + 0.3f*gp[4+i]);
  *(uint4*)(out + base) = *(uint4*)o;
}

__global__ void bo_kernel(const float* __restrict__ ta_bo, const float* __restrict__ tr_w1,
                          float* __restrict__ bo_f)
{
  int c = threadIdx.x;
  float s = 0.f;
  for(int m=0;m<256;m++) s += ta_bo[m]*tr_w1[(size_t)(256+m)*512 + c];
  bo_f[c] = s;
}

// ---------------------------------------------------------------------------
// Persistent scan. 128 blocks x 512 threads — proven X/Y two-hop topology.
// role = bid>>4: 0..3 = X (attention head), 4..7 = Y (MLP quarter-shard).
//
// R3 changes (chain-segment removal):
//  1. Softmax 16-group combine moved OFF-chain: shadow -> B_S -> wave0 combines
//     into numS/mzS (parity-buffered). On-chain finalize is now ~10 ops.
//  2. Y B3 removed: per-wave Y completion flags (drain own stores, set flag).
//     X lanes 0..31 poll the 32 (shard,wave) flags.
//  3. dbuf gather via relaxed atomic loads (pipelined); float2 LDS reads in
//     all matvecs.
// Flags: [0..63] X ctx (b*4+hd)=t, [128..191] X shadow (cross-XCD),
//        [256..383] xcc table, [512..1023] Y fast (b4+ish)*8+w = t+1,
//        [1024..1535] Y shadow (cross-XCD).
// ---------------------------------------------------------------------------
__global__ __launch_bounds__(512, 1) void scan_kernel(
    const ushort* __restrict__ qtb, const ushort* __restrict__ Ubf,
    const float* __restrict__ Wf, const float* __restrict__ bo_f,
    float* cbuf, float* dbuf, int* flags,
    const float* __restrict__ ta_wk, const float* __restrict__ ta_wv,
    const float* __restrict__ ta_bk, const float* __restrict__ ta_bv,
    const float* __restrict__ tr_w2, const float* __restrict__ tr_b2,
    const float* __restrict__ ln3_g, const float* __restrict__ ln3_b,
    const float* __restrict__ ln4_g, const float* __restrict__ ln4_b,
    const float* __restrict__ h0, float* __restrict__ out_h)
{
  __shared__ __align__(16) float red[2][1024];
  __shared__ __align__(16) float pbuf[512];
  __shared__ __align__(16) float hbuf[256];
  __shared__ __align__(16) float ctxL[256];
  __shared__ __align__(16) float qbufS[2][64];
  __shared__ float mG[2][16], sG[2][16];
  __shared__ __align__(16) float numS[2][64];
  __shared__ float mzS[2][2];
  __shared__ float sLastP[4];
  __shared__ __align__(16) float glbuf[128];
  __shared__ int cp_same[4];
  extern __shared__ __align__(16) ushort dynL[];
  ushort* kcL = dynL;             // [512][66] u16
  ushort* vcL = dynL + 512*66;    // [512][66] u16

  const int tid = threadIdx.x;
  const int bid = blockIdx.x;
  const int b = bid & 15;
  const int role = bid >> 4;
  const int b4 = b*4;
  const int w8 = tid >> 6;

  if(role < 4){   // zero k/v caches (safety; tail never read by construction)
    for(int i = tid; i < 512*66; i += 512){ kcL[i] = 0; vcL[i] = 0; }
  }

  // ---- one-time XCD handshake ----
  int myxcc;
  asm volatile("s_getreg_b32 %0, hwreg(HW_REG_XCC_ID)" : "=s"(myxcc));
  if(tid == 0)
    __hip_atomic_store(&flags[256 + bid], myxcc + 1, __ATOMIC_RELEASE, __HIP_MEMORY_SCOPE_AGENT);
  if(tid < 4){
    int cbid = (role < 4) ? (64 + tid*16 + b) : (tid*16 + b);
    int v;
    while((v = __hip_atomic_load(&flags[256 + cbid], __ATOMIC_ACQUIRE, __HIP_MEMORY_SCOPE_AGENT)) == 0)
      __builtin_amdgcn_s_sleep(8);
    cp_same[tid] = ((v - 1) == myxcc);
  }
  __syncthreads();
  const int anyrem = !(cp_same[0] && cp_same[1] && cp_same[2] && cp_same[3]);

  if(role < 4){
    // ================= X: attention head hd =================
    const int hd = role;
    const int bh = b4 + hd;
    // matvec: thread = out*4 + s; out<64 -> k col, out>=64 -> v col.
    const int out = tid >> 2, sX = tid & 3;
    const int kvSel = out >> 6, colX = out & 63;
    const float* WX = kvSel ? ta_wv : ta_wk;
    uint wp[32];
#pragma unroll
    for(int i=0;i<32;i++){
      int r0 = 8*i + 2*sX;
      wp[i] = pack_bf2(WX[(size_t)r0*256 + hd*64 + colX],
                       WX[(size_t)(r0+1)*256 + hd*64 + colX]);
    }
    const float pbX = kvSel ? ta_bv[hd*64 + colX] : ta_bk[hd*64 + colX];
    // wave0 LN state (lane l owns cols 4l..4l+3)
    float h4[4], b2r4[4], g34[4], b34[4];
    if(tid < 64){
#pragma unroll
      for(int c=0;c<4;c++){
        int d = 4*tid + c;
        h4[c] = h0[b*256 + d]; b2r4[c] = tr_b2[d]; g34[c] = ln3_g[d]; b34[c] = ln3_b[d];
      }
      *(float4*)&hbuf[4*tid] = *(float4*)h4;
    }
    // shadow row mapping: threads 64..511 -> rows 0..447; wave0 -> rows 448..511
    const int j_sh = (tid >= 64) ? (tid - 64) : (448 + tid);
    const int gsh = j_sh >> 5;       // group 0..15 (32 rows each)
    const int lsh = tid & 31;        // lane within group (d-pair owner)
    __syncthreads();

    // q prefetch (row 1) — wave 7 stages q into LDS each step (double-buffered)
    ushort qpre = 0;
    if(tid >= 448) qpre = qtb[((size_t)(b*512 + 1))*256 + hd*64 + (tid - 448)];

#pragma clang loop unroll(disable)
    for(int t=0;t<512;t++){
      // stage q_{t+1} into slot (t+1)&1; issue q_{t+2} load
      if(tid >= 448){
        qbufS[(t+1)&1][tid-448] = b2f(qpre)*0.125f;
        int tq = (t+2 < 512) ? (t+2) : 511;
        qpre = qtb[((size_t)(b*512 + tq))*256 + hd*64 + (tid - 448)];
      }
      if(t > 0){
        // [K] k/v row t-1 from h_t (in hbuf); last-row score partial via shuffle
        float acc = 0.f;
#pragma unroll
        for(int i=0;i<32;i++){
          float2 hv = *(const float2*)&hbuf[8*i + 2*sX];
          acc += hv.x*lo16(wp[i]) + hv.y*hi16(wp[i]);
        }
        acc += __shfl_xor(acc, 1);
        acc += __shfl_xor(acc, 2);
        float kf = acc + pbX;
        if(sX == 0){
          ushort u = f2b(kf);
          if(kvSel == 0) kcL[(t-1)*66 + colX] = u;
          else           vcL[(t-1)*66 + colX] = u;
        }
        // s_last = q_t . k_{t-1}: products live in lanes with sX==0, kvSel==0
        float pv = (kvSel == 0 && sX == 0) ? qbufS[t&1][colX]*kf : 0.f;
        pv += __shfl_xor(pv, 4);
        pv += __shfl_xor(pv, 8);
        pv += __shfl_xor(pv, 16);
        pv += __shfl_xor(pv, 32);
        if(tid < 256 && (tid & 63) == 0) sLastP[tid >> 6] = pv;
        __syncthreads();                                   // B1
        // [F] finalize-lite (wave0): old-part precombined in numS/mzS
        if(tid < 64){
          const int par = t & 1;
          float sl = (sLastP[0] + sLastP[1]) + (sLastP[2] + sLastP[3]);
          float mo = mzS[par][0], Zo = mzS[par][1];
          float m = fmaxf(mo, sl);
          float so = __expf(mo - m);
          float el = __expf(sl - m);
          float Z = Zo*so + el;
          float vlast = b2f(vcL[(t-1)*66 + tid]);
          cbuf[b*256 + hd*64 + tid] = (numS[par][tid]*so + el*vlast) / Z;
          asm volatile("s_waitcnt vmcnt(0)" ::: "memory");
          if(tid == 0){
            *(volatile int*)&flags[bh] = t;
            if(anyrem)
              __hip_atomic_store(&flags[128 + bh], t, __ATOMIC_RELEASE, __HIP_MEMORY_SCOPE_AGENT);
          }
        }
      } // t>0

      // [S] shadow for step t+1: rows j_sh <= t-1, write parity (t+1)&1.
      {
        const int par = (t+1)&1;
        float s = -3.0e38f;
        if(j_sh < t){
          const uint* kr = (const uint*)(kcL + j_sh*66);
          const float* qS = qbufS[par];
          float a = 0.f;
#pragma unroll
          for(int w=0; w<32; w++){
            uint kk = kr[w];
            float2 q2 = *(const float2*)&qS[2*w];
            a += q2.x*lo16(kk) + q2.y*hi16(kk);
          }
          s = a;
        }
        // 32-lane (group) reduce: offsets stay within half-wave
        float gm = s;
#pragma unroll
        for(int off=16; off; off>>=1) gm = fmaxf(gm, __shfl_xor(gm, off));
        float e = (j_sh < t) ? __expf(s - gm) : 0.f;
        pbuf[j_sh] = e;
        float gs = e;
#pragma unroll
        for(int off=16; off; off>>=1) gs += __shfl_xor(gs, off);
        if(lsh == 0){ mG[par][gsh] = gm; sG[par][gsh] = gs; }
        // partial ctx for this group: lane owns d-pair (2lsh, 2lsh+1)
        int nn = t - gsh*32; nn = nn < 0 ? 0 : (nn > 32 ? 32 : nn);
        float a0 = 0.f, a1 = 0.f;
        const uint* vbase = (const uint*)vcL;
#pragma unroll 4
        for(int i=0;i<nn;i++){
          int j2 = gsh*32 + i;
          uint vv = vbase[j2*33 + lsh];
          float p = pbuf[j2];
          a0 += p*lo16(vv); a1 += p*hi16(vv);
        }
        float2 pr; pr.x = a0; pr.y = a1;
        *(float2*)&red[par][gsh*64 + 2*lsh] = pr;
      }
      __syncthreads();                                     // B_S
      // [C] wave0 combine (off-chain, absorbed in Y-wait): 16 groups -> numS/mzS
      if(tid < 64){
        const int par = (t+1)&1;
        float mo = mG[par][0];
#pragma unroll
        for(int g=1; g<16; g++) mo = fmaxf(mo, mG[par][g]);
        float Zo = 0.f, nm = 0.f;
#pragma unroll
        for(int g=0; g<16; g++){
          float scl = __expf(mG[par][g] - mo);
          Zo += sG[par][g]*scl;
          nm += red[par][g*64 + tid]*scl;
        }
        numS[par][tid] = nm;
        if(tid == 0){ mzS[par][0] = mo; mzS[par][1] = Zo; }
      }
      // wave0 lanes 0..31: poll 32 per-wave Y flags
      if(tid < 32){
        const int sh = tid >> 3, wv = tid & 7;
        if(cp_same[sh]){
          while(*(volatile int*)&flags[512 + (b4+sh)*8 + wv] < t+1) __builtin_amdgcn_s_sleep(1);
        } else {
          while(__hip_atomic_load(&flags[1024 + (b4+sh)*8 + wv], __ATOMIC_RELAXED, __HIP_MEMORY_SCOPE_AGENT) < t+1)
            __builtin_amdgcn_s_sleep(2);
        }
      }
      if(tid < 64){
        if(anyrem) __builtin_amdgcn_fence(__ATOMIC_ACQUIRE, "agent");
        float ds[4] = {0.f,0.f,0.f,0.f};
#pragma unroll
        for(int i=0;i<4;i++){
          const float* dp = &dbuf[(b4+i)*256 + 4*tid];
#pragma unroll
          for(int c=0;c<4;c++)
            ds[c] += __hip_atomic_load(dp + c, __ATOMIC_RELAXED, __HIP_MEMORY_SCOPE_AGENT);
        }
        float v4[4]; float s1 = 0.f, s2 = 0.f;
#pragma unroll
        for(int c=0;c<4;c++){
          v4[c] = h4[c] + 0.5f*(ds[c] + b2r4[c]);
          s1 += v4[c]; s2 += v4[c]*v4[c];
        }
#pragma unroll
        for(int off=32; off; off>>=1){ s1 += __shfl_xor(s1,off); s2 += __shfl_xor(s2,off); }
        float mu = s1*(1.f/256.f);
        float qq = s2*(1.f/256.f) - mu*mu;
        float rstd = rsqrtf(qq + 1e-5f);
#pragma unroll
        for(int c=0;c<4;c++) h4[c] = (v4[c]-mu)*rstd*g34[c] + b34[c];
        *(float4*)&hbuf[4*tid] = *(float4*)h4;
      }
      __syncthreads();                                     // B_LN
    } // t loop

    if(hd == 0 && tid < 64){
      float s1 = 0.f, s2 = 0.f;
#pragma unroll
      for(int c=0;c<4;c++){ s1 += h4[c]; s2 += h4[c]*h4[c]; }
#pragma unroll
      for(int off=32; off; off>>=1){ s1 += __shfl_xor(s1,off); s2 += __shfl_xor(s2,off); }
      float mu = s1*(1.f/256.f);
      float qq = s2*(1.f/256.f) - mu*mu;
      float rstd = rsqrtf(qq + 1e-5f);
#pragma unroll
      for(int c=0;c<4;c++){
        int d = 4*tid + c;
        out_h[b*256 + d] = (h4[c]-mu)*rstd*ln4_g[d] + ln4_b[d];
      }
    }
  } else {
    // ================= Y: MLP quarter-shard ish (128 hidden) =================
    const int ish = role - 4;
    // Wf matvec: thread = hid*4 + sY (hid<128)
    const int hid = tid >> 2, sY = tid & 3;
    const int colY = ish*128 + hid;
    uint wfp[32];
#pragma unroll
    for(int i=0;i<32;i++){
      int r0 = 8*i + 2*sY;
      wfp[i] = pack_bf2(Wf[(size_t)r0*512 + colY], Wf[(size_t)(r0+1)*512 + colY]);
    }
    // w2 matvec: thread = dcol*2 + s2 (dcol<256), local hidden rows 4i+2*s2
    const int dcol = tid >> 1, s2 = tid & 1;
    uint w2p[32];
#pragma unroll
    for(int i=0;i<32;i++){
      int r0 = ish*128 + 4*i + 2*s2;
      w2p[i] = pack_bf2(tr_w2[(size_t)r0*256 + dcol], tr_w2[(size_t)(r0+1)*256 + dcol]);
    }
    const float borr = (sY==0) ? bo_f[colY] : 0.f;
    __syncthreads();

#pragma clang loop unroll(disable)
    for(int t=0;t<512;t++){
      ushort uvs = 0;
      if(sY == 0) uvs = Ubf[((size_t)(b*512 + t))*512 + colY];
      if(t > 0){
        if(tid < 256){
          int q = tid >> 6;
          if(cp_same[q]){
            while(*(volatile int*)&flags[b4 + q] < t) __builtin_amdgcn_s_sleep(1);
          } else {
            while(__hip_atomic_load(&flags[128 + b4 + q], __ATOMIC_RELAXED, __HIP_MEMORY_SCOPE_AGENT) < t)
              __builtin_amdgcn_s_sleep(2);
          }
        }
        if(anyrem) __builtin_amdgcn_fence(__ATOMIC_ACQUIRE, "agent");
        if(tid < 256) ctxL[tid] = *(volatile float*)&cbuf[b*256 + tid];
      }
      __syncthreads();                                     // B1
      float accf = 0.f;
      if(t > 0){
#pragma unroll
        for(int i=0;i<32;i++){
          float2 c2 = *(const float2*)&ctxL[8*i + 2*sY];
          accf += c2.x*lo16(wfp[i]) + c2.y*hi16(wfp[i]);
        }
        accf += __shfl_xor(accf, 1);
        accf += __shfl_xor(accf, 2);
      }
      if(sY == 0){
        float g1 = b2f(uvs) + ((t>0) ? (borr + accf) : 0.f);
        glbuf[hid] = gelu_exact(g1);
      }
      __syncthreads();                                     // B2
      {
        float dp = 0.f;
#pragma unroll
        for(int i=0;i<32;i++){
          float2 gv = *(const float2*)&glbuf[4*i + 2*s2];
          dp += gv.x*lo16(w2p[i]) + gv.y*hi16(w2p[i]);
        }
        dp += __shfl_xor(dp, 1);
        if(s2 == 0) dbuf[(b4+ish)*256 + dcol] = dp;
      }
      // per-wave completion: drain own stores, set per-wave flag (no barrier)
      asm volatile("s_waitcnt vmcnt(0)" ::: "memory");
      if((tid & 63) == 0){
        *(volatile int*)&flags[512 + (b4+ish)*8 + w8] = t+1;
        if(anyrem)
          __hip_atomic_store(&flags[1024 + (b4+ish)*8 + w8], t+1, __ATOMIC_RELEASE, __HIP_MEMORY_SCOPE_AGENT);
      }
    }
  }
}

// ---------------------------------------------------------------------------
// Workspace layout (bytes).
// ---------------------------------------------------------------------------
#define OFF_FLAGS ((size_t)0)          // 8 KiB (1536 ints used)
#define OFF_BOF   ((size_t)8192)       // 2 KiB
#define OFF_CBUF  ((size_t)16384)      // 16 KiB
#define OFF_DBUF  ((size_t)32768)      // 64 KiB
#define OFF_GUID  ((size_t)98304)      // 16 KiB
#define OFF_WF    ((size_t)131072)     // 512 KiB -> ends 655360
#define OFF_Z1    ((size_t)(1u<<20))
#define OFF_Z2    ((size_t)(5u<<20))
#define OFF_Z3    ((size_t)(9u<<20))
#define OFF_Z4    ((size_t)(13u<<20))
#define OFF_M     ((size_t)(17u<<20))

#define SCAN_DYN_LDS (512*66*2*2)   // 135168 B

extern "C" void kernel_launch(void* const* d_in, const int* in_sizes, int n_in,
                              void* d_out, int out_size, void* d_ws, size_t ws_size,
                              hipStream_t stream)
{
  const float* x     = (const float*)d_in[0];
  const float* h0    = (const float*)d_in[1];
  const float* sa_wq = (const float*)d_in[2];
  const float* sa_wk = (const float*)d_in[3];
  const float* sa_wv = (const float*)d_in[4];
  const float* sa_wo = (const float*)d_in[5];
  const float* sa_bq = (const float*)d_in[6];
  const float* sa_bk = (const float*)d_in[7];
  const float* sa_bv = (const float*)d_in[8];
  const float* sa_bo = (const float*)d_in[9];
  const float* f_w1  = (const float*)d_in[10];
  const float* f_b1  = (const float*)d_in[11];
  const float* f_w2  = (const float*)d_in[12];
  const float* f_b2  = (const float*)d_in[13];
  const float* ta_wq = (const float*)d_in[14];
  const float* ta_wk = (const float*)d_in[15];
  const float* ta_wv = (const float*)d_in[16];
  const float* ta_wo = (const float*)d_in[17];
  const float* ta_bq = (const float*)d_in[18];
  const float* ta_bk = (const float*)d_in[19];
  const float* ta_bv = (const float*)d_in[20];
  const float* ta_bo = (const float*)d_in[21];
  const float* tr_w1 = (const float*)d_in[22];
  const float* tr_b1 = (const float*)d_in[23];
  const float* tr_w2 = (const float*)d_in[24];
  const float* tr_b2 = (const float*)d_in[25];
  const float* ps_w  = (const float*)d_in[26];
  const float* ps_b  = (const float*)d_in[27];
  const float* sp_w  = (const float*)d_in[28];
  const float* sp_b  = (const float*)d_in[29];
  const float* ln1_g = (const float*)d_in[30];
  const float* ln1_b = (const float*)d_in[31];
  const float* ln2_g = (const float*)d_in[32];
  const float* ln2_b = (const float*)d_in[33];
  const float* ln3_g = (const float*)d_in[34];
  const float* ln3_b = (const float*)d_in[35];
  const float* ln4_g = (const float*)d_in[36];
  const float* ln4_b = (const float*)d_in[37];

  char* ws = (char*)d_ws;
  int*    flags = (int*)   (ws + OFF_FLAGS);
  float*  bo_f  = (float*) (ws + OFF_BOF);
  float*  cbuf  = (float*) (ws + OFF_CBUF);
  float*  dbuf  = (float*) (ws + OFF_DBUF);
  float*  guid  = (float*) (ws + OFF_GUID);
  float*  Wff   = (float*) (ws + OFF_WF);
  ushort* qb    = (ushort*)(ws + OFF_Z1);
  ushort* kb    = (ushort*)(ws + OFF_Z2);
  ushort* vb    = (ushort*)(ws + OFF_Z3);
  ushort* attnb = (ushort*)(ws + OFF_Z4);
  float*  x0pre = (float*) (ws + OFF_Z1);
  float*  x1f   = (float*) (ws + OFF_Z3);
  ushort* ffnb  = (ushort*)(ws + OFF_M);
  ushort* mid   = (ushort*)(ws + OFF_M + (4u<<20));
  float*  x2pre = (float*) (ws + OFF_Z1);
  ushort* abf   = (ushort*)(ws + OFF_Z4);
  ushort* qtb   = (ushort*)(ws + OFF_Z3);
  ushort* Ubf   = (ushort*)(ws + OFF_M);
  float*  outb  = (float*)d_out;
  float*  out_h = outb + (out_size - 4096);

  static int attr_done = 0;
  if(!attr_done){
    hipFuncSetAttribute((const void*)scan_kernel,
                        hipFuncAttributeMaxDynamicSharedMemorySize, SCAN_DYN_LDS);
    attr_done = 1;
  }

  hipMemsetAsync(flags, 0, 8192, stream);

  // ===== parallel prefix =====
  gemm_kernel<1,0><<<512, 256, 0, stream>>>(x, sa_wq, 256, sa_bq, nullptr, nullptr, qb, 8192,256,256, 1.0f);
  gemm_kernel<1,0><<<512, 256, 0, stream>>>(x, sa_wk, 256, sa_bk, nullptr, nullptr, kb, 8192,256,256, 1.0f);
  gemm_kernel<1,0><<<512, 256, 0, stream>>>(x, sa_wv, 256, sa_bv, nullptr, nullptr, vb, 8192,256,256, 1.0f);
  attn_kernel<<<2048, 256, 0, stream>>>(qb, kb, vb, attnb);
  gemm_kernel<0,0><<<512, 256, 0, stream>>>(attnb, sa_wo, 256, sa_bo, x, x0pre, nullptr, 8192,256,256, 1.0f);
  ln_kernel<<<2048, 256, 0, stream>>>(x0pre, ln1_g, ln1_b, x1f, nullptr);
  guid_kernel<<<16, 256, 0, stream>>>(h0, sp_w, sp_b, guid);
  ffnin_kernel<<<1024, 256, 0, stream>>>(x1f, guid, ffnb);
  gemm_kernel<0,1><<<1024, 256, 0, stream>>>(ffnb, f_w1, 1024, f_b1, nullptr, nullptr, mid, 8192,512,256, 1.0f);
  gemm_kernel<0,0><<<512, 256, 0, stream>>>(mid, f_w2, 256, f_b2, x1f, x2pre, nullptr, 8192,256,512, 1.0f);
  gemm_kernel<0,1><<<1024, 256, 0, stream>>>(ffnb, f_w1 + 512, 1024, f_b1 + 512, nullptr, nullptr, mid, 8192,512,256, 1.0f);
  gemm_kernel<0,0><<<512, 256, 0, stream>>>(mid, f_w2 + (size_t)512*256, 256, nullptr, x2pre, x2pre, nullptr, 8192,256,512, 1.0f);
  ln_kernel<<<2048, 256, 0, stream>>>(x2pre, ln2_g, ln2_b, outb, nullptr);   // output 0 (f32)

  // ===== scan precompute (all GEMMs) =====
  gemm_kernel<1,0><<<512, 256, 0, stream>>>(outb, ps_w, 256, ps_b, outb, nullptr, abf, 8192,256,256, 0.3f);
  gemm_kernel<0,0><<<1024, 256, 0, stream>>>(abf, tr_w1, 512, tr_b1, nullptr, nullptr, Ubf, 8192,512,256, 1.0f);
  gemm_kernel<1,0><<<512, 256, 0, stream>>>(outb, ta_wq, 256, ta_bq, nullptr, nullptr, qtb, 8192,256,256, 1.0f);
  gemm_kernel<1,0><<<32, 256, 0, stream>>>(ta_wo, tr_w1 + (size_t)256*512, 512, nullptr, nullptr, Wff, nullptr, 256,512,256, 1.0f);
  bo_kernel<<<1, 512, 0, stream>>>(ta_bo, tr_w1, bo_f);

  // ===== sequential scan (persistent, LDS k/v caches, shadowed scores) =====
  scan_kernel<<<128, 512, SCAN_DYN_LDS, stream>>>(qtb, Ubf, Wff, bo_f, cbuf, dbuf, flags,
                                                  ta_wk, ta_wv, ta_bk, ta_bv, tr_w2, tr_b2,
                                                  ln3_g, ln3_b, ln4_g, ln4_b, h0, out_h);
}